// Round 4
// baseline (330.079 us; speedup 1.0000x reference)
//
#include <hip/hip_runtime.h>
#include <hip/hip_bf16.h>
#include <hip/hip_fp16.h>

typedef __hip_bfloat16 bf16;
typedef __attribute__((ext_vector_type(8))) short short8;   // 8 bf16 (4 VGPRs)
typedef __attribute__((ext_vector_type(4))) float f32x4;    // MFMA accumulator

#define MFMA16(a, b, c) __builtin_amdgcn_mfma_f32_16x16x32_bf16((a), (b), (c), 0, 0, 0)

// dual-mode float load: f32 ? float buffer : bf16 buffer (same element index)
static __device__ __forceinline__ float ldf(const void* p, long long i, bool f32) {
    return f32 ? ((const float*)p)[i] : __bfloat162float(((const bf16*)p)[i]);
}

static __device__ __forceinline__ short f2bs(float v) {
    union { bf16 h; short s; } u; u.h = __float2bfloat16(v); return u.s;
}

static __device__ __forceinline__ unsigned int pack_bf16x2(float a, float b) {
    return (unsigned int)(unsigned short)f2bs(a) | ((unsigned int)(unsigned short)f2bs(b) << 16);
}

// ---------------------------------------------------------------- encoding sniffer
// flags[0]: x is fp32?  flags[1]: weights are fp32?  flags[2]: edge_index is int64?
// MEASURED (R1 NaN-fail + R8 gating probe): this harness delivers x=fp32, W=fp32, out=fp32.
__global__ __launch_bounds__(256, 4)
void sniff_kernel(const void* __restrict__ x, const void* __restrict__ w,
                  const int* __restrict__ ei, int E, int* __restrict__ flags) {
    __shared__ int cnt;
    if (threadIdx.x == 0) cnt = 0;
    __syncthreads();
    if (blockIdx.x < 2) {
        const unsigned short* u = (const unsigned short*)(blockIdx.x == 0 ? x : w);
        int bad = 0;
        for (int i = threadIdx.x; i < 4096; i += 256) {
            unsigned e = (u[i] >> 7) & 0xFF;
            if (e >= 0xA0) bad++;
        }
        atomicAdd(&cnt, bad);
        __syncthreads();
        if (threadIdx.x == 0) flags[blockIdx.x] = (cnt > 16) ? 1 : 0;
    } else {
        int nz = 0;
        for (int i = threadIdx.x; i < 1024; i += 256)
            if (ei[2 * i + 1] != 0) nz++;
        atomicAdd(&cnt, nz);
        __syncthreads();
        if (threadIdx.x == 0) flags[2] = (cnt == 0) ? 1 : 0;
    }
}

static __device__ __forceinline__ int ld_src(const int* ei, int E, int e, bool i64) {
    return i64 ? ei[2 * e] : ei[e];
}
static __device__ __forceinline__ int ld_dst(const int* ei, int E, int e, bool i64) {
    return i64 ? ei[2 * (E + e)] : ei[E + e];
}

// ---------------------------------------------------------------- bucket CSR build
// shift=9: bucket b owns dst in [b*512, (b+1)*512). NB = ceil(N/512) <= 256.

// Pass A: global bucket histogram (LDS hist per block, 1 global add per bucket)
__global__ __launch_bounds__(256, 4)
void bhist_kernel(const int* __restrict__ ei, int E, const int* __restrict__ flags,
                  int shift, int NB, int* __restrict__ bucketCount) {
    __shared__ int h[256];
    for (int i = threadIdx.x; i < 256; i += 256) h[i] = 0;
    __syncthreads();
    bool i64 = flags[2] != 0;
    int base = blockIdx.x * 4096;
    for (int i = 0; i < 16; i++) {
        int e = base + i * 256 + threadIdx.x;
        if (e < E) atomicAdd(&h[ld_dst(ei, E, e, i64) >> shift], 1);
    }
    __syncthreads();
    for (int i = threadIdx.x; i < NB; i += 256)
        if (h[i]) atomicAdd(&bucketCount[i], h[i]);
}

// Pass B scan: bucketBase = exclusive scan; bcursor seeded with bases
__global__ __launch_bounds__(256, 4)
void bscan_kernel(const int* __restrict__ bucketCount, int NB,
                  int* __restrict__ bucketBase, int* __restrict__ bcursor, int E) {
    __shared__ int bs[256];
    int v = ((int)threadIdx.x < NB) ? bucketCount[threadIdx.x] : 0;
    bs[threadIdx.x] = v;
    __syncthreads();
    for (int off = 1; off < 256; off <<= 1) {
        int t = ((int)threadIdx.x >= off) ? bs[threadIdx.x - off] : 0;
        __syncthreads();
        bs[threadIdx.x] += t;
        __syncthreads();
    }
    int excl = bs[threadIdx.x] - v;
    if ((int)threadIdx.x < NB) { bucketBase[threadIdx.x] = excl; bcursor[threadIdx.x] = excl; }
    if (threadIdx.x == 0) bucketBase[NB] = E;
}

// Pass C: partition edges into bucket-contiguous ebuf (int2: x=src, y=dst)
// R4: 4096-edge chunk cached in 32KB LDS during sweep 1 — kills the second
// 25.6MB read of ei.
__global__ __launch_bounds__(256, 4)
void bpart_kernel(const int* __restrict__ ei, int E, const int* __restrict__ flags,
                  int shift, int NB, int* __restrict__ bcursor, int2* __restrict__ ebuf) {
    __shared__ int h[256];
    __shared__ int gofs[256];
    __shared__ int2 se[4096];    // 32KB edge cache
    for (int i = threadIdx.x; i < 256; i += 256) h[i] = 0;
    __syncthreads();
    bool i64 = flags[2] != 0;
    int base = blockIdx.x * 4096;
    // sweep 1: local histogram + LDS cache
    for (int i = 0; i < 16; i++) {
        int e = base + i * 256 + threadIdx.x;
        if (e < E) {
            int s = ld_src(ei, E, e, i64), d = ld_dst(ei, E, e, i64);
            se[i * 256 + threadIdx.x] = make_int2(s, d);
            atomicAdd(&h[d >> shift], 1);
        }
    }
    __syncthreads();
    // claim contiguous global ranges (1 atomic per bucket per block)
    if ((int)threadIdx.x < NB) {
        int c = h[threadIdx.x];
        gofs[threadIdx.x] = c ? atomicAdd(&bcursor[threadIdx.x], c) : 0;
    }
    __syncthreads();
    for (int i = threadIdx.x; i < 256; i += 256) h[i] = 0;
    __syncthreads();
    // sweep 2: write edges into claimed dense runs (from LDS)
    for (int i = 0; i < 16; i++) {
        int e = base + i * 256 + threadIdx.x;
        if (e < E) {
            int2 v = se[i * 256 + threadIdx.x];
            int b = v.y >> shift;
            int p = atomicAdd(&h[b], 1);
            ebuf[gofs[b] + p] = v;
        }
    }
}

// Pass D: one block per bucket — local count, scan, rowptr+dinv write, csr fill.
// All csr writes land in one block's ~32KB window (single XCD L2; no line ping-pong).
__global__ __launch_bounds__(256, 2)
void bbuild_kernel(const int2* __restrict__ ebuf, const int* __restrict__ bucketBase,
                   int shift, int N, int E, int* __restrict__ rowptr,
                   float* __restrict__ dinv, int* __restrict__ csr_src) {
    __shared__ int cnt[1024];
    __shared__ int exc[1024];
    __shared__ int bs[256];
    int b = blockIdx.x;
    int nodeBase = b << shift;
    int width = 1 << shift;
    int nn = N - nodeBase; if (nn > width) nn = width;
    int beg = bucketBase[b], end = bucketBase[b + 1];
    for (int i = threadIdx.x; i < width; i += 256) cnt[i] = 0;
    __syncthreads();
    for (int e = beg + threadIdx.x; e < end; e += 256)
        atomicAdd(&cnt[ebuf[e].y - nodeBase], 1);
    __syncthreads();
    // exclusive scan of cnt[0..width)
    int per = width / 256;          // 2 at shift=9
    int s = 0;
    int base4 = threadIdx.x * per;
    for (int i = 0; i < per; i++) s += cnt[base4 + i];
    bs[threadIdx.x] = s;
    __syncthreads();
    for (int off = 1; off < 256; off <<= 1) {
        int t = ((int)threadIdx.x >= off) ? bs[threadIdx.x - off] : 0;
        __syncthreads();
        bs[threadIdx.x] += t;
        __syncthreads();
    }
    int run = bs[threadIdx.x] - s;
    for (int i = 0; i < per; i++) { exc[base4 + i] = run; run += cnt[base4 + i]; }
    __syncthreads();
    // rowptr + dinv (coalesced)
    for (int i = threadIdx.x; i < nn; i += 256) {
        int node = nodeBase + i;
        rowptr[node] = beg + exc[i];
        dinv[node] = rsqrtf((float)cnt[i] + 1.0f);
    }
    __syncthreads();
    for (int i = threadIdx.x; i < width; i += 256) cnt[i] = 0;
    __syncthreads();
    // csr fill within local window
    for (int e = beg + threadIdx.x; e < end; e += 256) {
        int2 v = ebuf[e];
        int l = v.y - nodeBase;
        int p = atomicAdd(&cnt[l], 1);
        csr_src[beg + exc[l] + p] = v.x;
    }
    if (b == 0 && threadIdx.x == 0) rowptr[N] = E;
}

// ---------------------------------------------------------------- weight -> MFMA B-fragment packs
// frag f = kstep*ntiles + ntile; slot s = f*64 + lane; element j (0..7):
//   W[kstep*32 + (lane>>4)*8 + j][ntile*16 + (lane&15)]  (fw-aware fp32/bf16 read)
__global__ __launch_bounds__(256, 4)
void repack_kernel(const void* __restrict__ W1, const void* __restrict__ W2,
                   const void* __restrict__ Wl, const int* __restrict__ flags,
                   bf16* __restrict__ Bp1, bf16* __restrict__ Bp2, bf16* __restrict__ Bp3) {
    bool fw = flags[1] != 0;
    const void* W; bf16* Bp; int ntiles, nc, nfrag;
    if (blockIdx.x == 0)      { W = W1; Bp = Bp1; ntiles = 4; nc = 64; nfrag = 16; }
    else if (blockIdx.x == 1) { W = W2; Bp = Bp2; ntiles = 2; nc = 32; nfrag = 4;  }
    else                      { W = Wl; Bp = Bp3; ntiles = 2; nc = 32; nfrag = 14; }
    for (int s = threadIdx.x; s < nfrag * 64; s += 256) {
        int f = s >> 6, lane = s & 63;
        int kstep = f / ntiles, ntile = f % ntiles;
        int n = ntile * 16 + (lane & 15);
        int kbase = kstep * 32 + (lane >> 4) * 8;
#pragma unroll
        for (int j = 0; j < 8; j++)
            Bp[s * 8 + j] = __float2bfloat16(ldf(W, (long long)(kbase + j) * nc + n, fw));
    }
}

// ---------------------------------------------------------------- x -> xb (bf16), both source dtypes
__global__ __launch_bounds__(256, 4)
void cvt_x_kernel(const void* __restrict__ x, const int* __restrict__ flags,
                  short* __restrict__ xb, long long total8) {
    long long i = (long long)blockIdx.x * 256 + threadIdx.x;
    if (i >= total8) return;
    bool fx = flags[0] != 0;
    short8 o;
    if (fx) {
        const float4* xf = (const float4*)x;
        float4 a = xf[i * 2], b = xf[i * 2 + 1];
        o[0] = f2bs(a.x); o[1] = f2bs(a.y); o[2] = f2bs(a.z); o[3] = f2bs(a.w);
        o[4] = f2bs(b.x); o[5] = f2bs(b.y); o[6] = f2bs(b.z); o[7] = f2bs(b.w);
    } else {
        o = ((const short8*)x)[i];
    }
    ((short8*)xb)[i] = o;
}

// ---------------------------------------------------------------- GEMM1 (MFMA): xb[N,128]@W1 -> h1g[N,64] f16 rows
// Epilogue scales row r by dinv[r] and stores f16 (rel err 2^-11, negligible vs
// the bf16 rounding already applied downstream).  128B rows halve the gather's
// L2-miss volume (the measured 3.7 TB/s wall is miss-volume-bound).
__global__ __launch_bounds__(256, 3)
void gemm1_mfma_kernel(const short* __restrict__ xb, const bf16* __restrict__ Bpack,
                       const float* __restrict__ dinv, __half* __restrict__ h1g, int N) {
    int lane = threadIdx.x & 63, wave = threadIdx.x >> 6;
    int m = lane & 15, quad = lane >> 4;
    int base = blockIdx.x * 128 + wave * 32;
    if (base >= N) return;
    const short8* bp = (const short8*)Bpack;
    short8 B[16];
#pragma unroll
    for (int i = 0; i < 16; i++) B[i] = bp[i * 64 + lane];
    if (base + 32 <= N) {
#pragma unroll
        for (int t = 0; t < 2; t++) {
            int r0 = base + t * 16;
            const short* xr = &xb[(long long)(r0 + m) * 128 + quad * 8];
            short8 A[4];
#pragma unroll
            for (int k = 0; k < 4; k++) A[k] = *(const short8*)(xr + k * 32);
            f32x4 acc[4];
#pragma unroll
            for (int nt = 0; nt < 4; nt++) acc[nt] = (f32x4){0.f, 0.f, 0.f, 0.f};
#pragma unroll
            for (int k = 0; k < 4; k++) {
#pragma unroll
                for (int nt = 0; nt < 4; nt++) acc[nt] = MFMA16(A[k], B[k * 4 + nt], acc[nt]);
            }
            // C/D: col = lane&15, row = quad*4 + r  [m89/m91]
            float dv[4];
#pragma unroll
            for (int r = 0; r < 4; r++) dv[r] = dinv[r0 + quad * 4 + r];
            __half* o = &h1g[(long long)(r0 + quad * 4) * 64 + m];
#pragma unroll
            for (int nt = 0; nt < 4; nt++) {
#pragma unroll
                for (int r = 0; r < 4; r++) o[(long long)r * 64 + nt * 16] = __float2half(acc[nt][r] * dv[r]);
            }
        }
    } else {
#pragma unroll
        for (int t = 0; t < 2; t++) {
            int r0 = base + t * 16;
            int row = r0 + m;
            short8 A[4];
#pragma unroll
            for (int k = 0; k < 4; k++) A[k] = (short8){0,0,0,0,0,0,0,0};
            if (row < N) {
                const short* xr = &xb[(long long)row * 128 + quad * 8];
#pragma unroll
                for (int k = 0; k < 4; k++) A[k] = *(const short8*)(xr + k * 32);
            }
            f32x4 acc[4];
#pragma unroll
            for (int nt = 0; nt < 4; nt++) acc[nt] = (f32x4){0.f, 0.f, 0.f, 0.f};
#pragma unroll
            for (int k = 0; k < 4; k++) {
#pragma unroll
                for (int nt = 0; nt < 4; nt++) acc[nt] = MFMA16(A[k], B[k * 4 + nt], acc[nt]);
            }
#pragma unroll
            for (int r = 0; r < 4; r++) {
                int orow = r0 + quad * 4 + r;
                if (orow < N) {
                    float dv = dinv[orow];
                    __half* o = &h1g[(long long)orow * 64 + m];
#pragma unroll
                    for (int nt = 0; nt < 4; nt++) o[nt * 16] = __float2half(acc[nt][r] * dv);
                }
            }
        }
    }
}

// ---------------------------------------------------------------- gather layer 1: one wave per NODE PAIR -> h1b (bf16 packed)
// R4: 2 nodes per wave.  Per-node latency chain {rowptr s_load -> csr s_loads ->
// row vloads -> reduce -> store} was the limiter (~2.8us/node at 58us).  Pairing
// merges rowptr loads (CSR-adjacent: beg1==end0), doubles row-loads in flight
// (16), and the two output rows store as one contiguous 256B wave store
// (half 0 -> n0, half 1 -> n1).
__global__ __launch_bounds__(256, 8)
void gather1_kernel(const unsigned int* __restrict__ h1g, const float* __restrict__ dinv,
                    const int* __restrict__ rowptr, const int* __restrict__ csr_src,
                    const void* __restrict__ bptr, const int* __restrict__ flags,
                    unsigned int* __restrict__ h1b, int N) {
    bool fw = flags[1] != 0;
    int lane = threadIdx.x & 63;
    int c = lane & 31, hf = lane >> 5;
    int wv = __builtin_amdgcn_readfirstlane(threadIdx.x >> 6);
    int n0 = blockIdx.x * 8 + wv * 2;
    if (n0 >= N) return;
    int n1 = (n0 + 1 < N) ? n0 + 1 : n0;
    int beg0 = rowptr[n0], end0 = rowptr[n0 + 1];
    int beg1 = rowptr[n1], end1 = rowptr[n1 + 1];
    const unsigned int* hL = h1g + c;
    float a00 = 0.f, a01 = 0.f, a10 = 0.f, a11 = 0.f;
    int p0 = beg0, p1 = beg1;
    while (p0 < end0 || p1 < end1) {
        unsigned int v0[8], v1[8]; float m0[8], m1[8];
#pragma unroll
        for (int u = 0; u < 8; u++) {
            int i00 = p0 + 2 * u, i01 = i00 + 1;
            int s00 = csr_src[(i00 < end0) ? i00 : beg0];   // uniform -> s_load
            int s01 = csr_src[(i01 < end0) ? i01 : beg0];
            int sA = hf ? s01 : s00;
            m0[u] = hf ? ((i01 < end0) ? 1.f : 0.f) : ((i00 < end0) ? 1.f : 0.f);
            v0[u] = hL[(long long)sA * 32];
            int i10 = p1 + 2 * u, i11 = i10 + 1;
            int s10 = csr_src[(i10 < end1) ? i10 : beg1];
            int s11 = csr_src[(i11 < end1) ? i11 : beg1];
            int sB = hf ? s11 : s10;
            m1[u] = hf ? ((i11 < end1) ? 1.f : 0.f) : ((i10 < end1) ? 1.f : 0.f);
            v1[u] = hL[(long long)sB * 32];
        }
#pragma unroll
        for (int u = 0; u < 8; u++) {
            float2 f0 = __half22float2(*(const __half2*)&v0[u]);
            a00 = fmaf(f0.x, m0[u], a00);
            a01 = fmaf(f0.y, m0[u], a01);
            float2 f1 = __half22float2(*(const __half2*)&v1[u]);
            a10 = fmaf(f1.x, m1[u], a10);
            a11 = fmaf(f1.y, m1[u], a11);
        }
        p0 += 16; p1 += 16;
    }
    a00 += __shfl_xor(a00, 32); a01 += __shfl_xor(a01, 32);
    a10 += __shfl_xor(a10, 32); a11 += __shfl_xor(a11, 32);
    // half 0 stores n0, half 1 stores n1 (contiguous 256B wave store)
    int node = hf ? n1 : n0;
    float a0 = hf ? a10 : a00;
    float a1 = hf ? a11 : a01;
    if (!(hf && n1 == n0)) {
        unsigned int gsv = h1g[(long long)node * 32 + c];
        float2 gs = __half22float2(*(const __half2*)&gsv);
        float dvd = dinv[node];
        float o0 = dvd * (a0 + gs.x) + ldf(bptr, 2 * c, fw);
        float o1 = dvd * (a1 + gs.y) + ldf(bptr, 2 * c + 1, fw);
        h1b[(long long)node * 32 + c] = pack_bf16x2(fmaxf(o0, 0.f), fmaxf(o1, 0.f));
    }
}

// ---------------------------------------------------------------- GEMM2 (MFMA): h1b[N,64]@W2 -> h2g[N,32] f16 rows (dinv-scaled)
__global__ __launch_bounds__(256, 4)
void gemm2_mfma_kernel(const short* __restrict__ h1b, const bf16* __restrict__ Bpack,
                       const float* __restrict__ dinv, __half* __restrict__ h2g, int N) {
    int lane = threadIdx.x & 63, wave = threadIdx.x >> 6;
    int m = lane & 15, quad = lane >> 4;
    int r0 = blockIdx.x * 64 + wave * 16;
    if (r0 >= N) return;
    const short8* bp = (const short8*)Bpack;
    short8 B[4];
#pragma unroll
    for (int i = 0; i < 4; i++) B[i] = bp[i * 64 + lane];
    f32x4 acc0 = {0.f,0.f,0.f,0.f}, acc1 = {0.f,0.f,0.f,0.f};
    if (r0 + 16 <= N) {
        const short* xr = &h1b[(long long)(r0 + m) * 64 + quad * 8];
#pragma unroll
        for (int k = 0; k < 2; k++) {
            short8 A = *(const short8*)(xr + k * 32);
            acc0 = MFMA16(A, B[k * 2 + 0], acc0);
            acc1 = MFMA16(A, B[k * 2 + 1], acc1);
        }
        float dv[4];
#pragma unroll
        for (int r = 0; r < 4; r++) dv[r] = dinv[r0 + quad * 4 + r];
        __half* o = &h2g[(long long)(r0 + quad * 4) * 32 + m];
#pragma unroll
        for (int r = 0; r < 4; r++) {
            o[(long long)r * 32]      = __float2half(acc0[r] * dv[r]);
            o[(long long)r * 32 + 16] = __float2half(acc1[r] * dv[r]);
        }
    } else {
        int row = r0 + m;
#pragma unroll
        for (int k = 0; k < 2; k++) {
            short8 A = {0,0,0,0,0,0,0,0};
            if (row < N) A = *(const short8*)&h1b[(long long)row * 64 + k * 32 + quad * 8];
            acc0 = MFMA16(A, B[k * 2 + 0], acc0);
            acc1 = MFMA16(A, B[k * 2 + 1], acc1);
        }
#pragma unroll
        for (int r = 0; r < 4; r++) {
            int orow = r0 + quad * 4 + r;
            if (orow < N) {
                float dv = dinv[orow];
                h2g[(long long)orow * 32 + m]      = __float2half(acc0[r] * dv);
                h2g[(long long)orow * 32 + 16 + m] = __float2half(acc1[r] * dv);
            }
        }
    }
}

// ---------------------------------------------------------------- gather layer 2: h2g (f16x2, 64B rows) -> h2b (bf16 packed)
// R4: 2 nodes per wave (same pipelining as gather1).  16-lane group per edge,
// 4 edges per node per u-step, 8 row-loads in flight.  Sub-groups 0/1 store
// the node pair (contiguous 128B store).
__global__ __launch_bounds__(256, 8)
void gather2_kernel(const unsigned int* __restrict__ h2g, const float* __restrict__ dinv,
                    const int* __restrict__ rowptr, const int* __restrict__ csr_src,
                    const void* __restrict__ bptr, const int* __restrict__ flags,
                    unsigned int* __restrict__ h2b, int N) {
    bool fw = flags[1] != 0;
    int lane = threadIdx.x & 63;
    int c = lane & 15, sub = lane >> 4;
    int wv = __builtin_amdgcn_readfirstlane(threadIdx.x >> 6);
    int n0 = blockIdx.x * 8 + wv * 2;
    if (n0 >= N) return;
    int n1 = (n0 + 1 < N) ? n0 + 1 : n0;
    int beg0 = rowptr[n0], end0 = rowptr[n0 + 1];
    int beg1 = rowptr[n1], end1 = rowptr[n1 + 1];
    const unsigned int* hL = h2g + c;
    float a00 = 0.f, a01 = 0.f, a10 = 0.f, a11 = 0.f;
    int p0 = beg0, p1 = beg1;
    while (p0 < end0 || p1 < end1) {
        unsigned int v0[4], v1[4]; float m0[4], m1[4];
#pragma unroll
        for (int u = 0; u < 4; u++) {
            {
                int i0 = p0 + 4 * u;
                int sa0 = csr_src[(i0     < end0) ? i0     : beg0];   // uniform -> s_load
                int sa1 = csr_src[(i0 + 1 < end0) ? i0 + 1 : beg0];
                int sa2 = csr_src[(i0 + 2 < end0) ? i0 + 2 : beg0];
                int sa3 = csr_src[(i0 + 3 < end0) ? i0 + 3 : beg0];
                int sA = (sub & 1) ? sa1 : sa0;
                int sB = (sub & 1) ? sa3 : sa2;
                int s  = (sub & 2) ? sB : sA;
                float ma = (sub & 1) ? ((i0 + 1 < end0) ? 1.f : 0.f) : ((i0 < end0) ? 1.f : 0.f);
                float mb = (sub & 1) ? ((i0 + 3 < end0) ? 1.f : 0.f) : ((i0 + 2 < end0) ? 1.f : 0.f);
                m0[u] = (sub & 2) ? mb : ma;
                v0[u] = hL[(long long)s * 16];
            }
            {
                int i1 = p1 + 4 * u;
                int sa0 = csr_src[(i1     < end1) ? i1     : beg1];
                int sa1 = csr_src[(i1 + 1 < end1) ? i1 + 1 : beg1];
                int sa2 = csr_src[(i1 + 2 < end1) ? i1 + 2 : beg1];
                int sa3 = csr_src[(i1 + 3 < end1) ? i1 + 3 : beg1];
                int sA = (sub & 1) ? sa1 : sa0;
                int sB = (sub & 1) ? sa3 : sa2;
                int s  = (sub & 2) ? sB : sA;
                float ma = (sub & 1) ? ((i1 + 1 < end1) ? 1.f : 0.f) : ((i1 < end1) ? 1.f : 0.f);
                float mb = (sub & 1) ? ((i1 + 3 < end1) ? 1.f : 0.f) : ((i1 + 2 < end1) ? 1.f : 0.f);
                m1[u] = (sub & 2) ? mb : ma;
                v1[u] = hL[(long long)s * 16];
            }
        }
#pragma unroll
        for (int u = 0; u < 4; u++) {
            float2 f0 = __half22float2(*(const __half2*)&v0[u]);
            a00 = fmaf(f0.x, m0[u], a00);
            a01 = fmaf(f0.y, m0[u], a01);
            float2 f1 = __half22float2(*(const __half2*)&v1[u]);
            a10 = fmaf(f1.x, m1[u], a10);
            a11 = fmaf(f1.y, m1[u], a11);
        }
        p0 += 16; p1 += 16;
    }
    a00 += __shfl_xor(a00, 16); a01 += __shfl_xor(a01, 16);
    a10 += __shfl_xor(a10, 16); a11 += __shfl_xor(a11, 16);
    a00 += __shfl_xor(a00, 32); a01 += __shfl_xor(a01, 32);
    a10 += __shfl_xor(a10, 32); a11 += __shfl_xor(a11, 32);
    // sub 0 stores n0, sub 1 stores n1 (contiguous 128B store); sub 2,3 idle
    if (sub < 2 && !(sub == 1 && n1 == n0)) {
        int node = sub ? n1 : n0;
        float a0 = sub ? a10 : a00;
        float a1 = sub ? a11 : a01;
        unsigned int gsv = h2g[(long long)node * 16 + c];
        float2 gs = __half22float2(*(const __half2*)&gsv);
        float dvd = dinv[node];
        float o0 = dvd * (a0 + gs.x) + ldf(bptr, 2 * c, fw);
        float o1 = dvd * (a1 + gs.y) + ldf(bptr, 2 * c + 1, fw);
        h2b[(long long)node * 16 + c] = pack_bf16x2(o0, o1);
    }
}

// ---------------------------------------------------------------- final (MFMA): [xb|h1b|h2b]@Wl + bl -> log_softmax
__global__ __launch_bounds__(256, 2)
void final_mfma_kernel(const short* __restrict__ xb, const short* __restrict__ h1b,
                       const short* __restrict__ h2b, const bf16* __restrict__ Bpack,
                       const void* __restrict__ bl, const int* __restrict__ flags,
                       void* __restrict__ out, int N) {
    bool fw = flags[1] != 0, fx = flags[0] != 0;
    int lane = threadIdx.x & 63, wave = threadIdx.x >> 6;
    int m = lane & 15, quad = lane >> 4;
    int r0 = blockIdx.x * 64 + wave * 16;
    if (r0 >= N) return;
    const short8* bp = (const short8*)Bpack;
    short8 B[14];
#pragma unroll
    for (int i = 0; i < 14; i++) B[i] = bp[i * 64 + lane];
    f32x4 acc0 = {0.f,0.f,0.f,0.f}, acc1 = {0.f,0.f,0.f,0.f};
    bool full = (r0 + 16 <= N);
    int row = r0 + m;
    bool rowok = full || (row < N);
#pragma unroll
    for (int s = 0; s < 7; s++) {
        short8 A = {0,0,0,0,0,0,0,0};
        if (rowok) {
            const short* p;
            if (s < 4)      p = &xb [(long long)row * 128 + s * 32 + quad * 8];
            else if (s < 6) p = &h1b[(long long)row * 64 + (s - 4) * 32 + quad * 8];
            else            p = &h2b[(long long)row * 32 + quad * 8];
            A = *(const short8*)p;
        }
        acc0 = MFMA16(A, B[s * 2 + 0], acc0);
        acc1 = MFMA16(A, B[s * 2 + 1], acc1);
    }
    float bl0 = ldf(bl, m, fw), bl1 = ldf(bl, m + 16, fw);
#pragma unroll
    for (int r = 0; r < 4; r++) {
        float v0 = acc0[r] + bl0, v1 = acc1[r] + bl1;
        float mx = fmaxf(v0, v1);
#pragma unroll
        for (int o = 8; o > 0; o >>= 1) mx = fmaxf(mx, __shfl_xor(mx, o));
        float sm = __expf(v0 - mx) + __expf(v1 - mx);
#pragma unroll
        for (int o = 8; o > 0; o >>= 1) sm += __shfl_xor(sm, o);
        float lse = mx + __logf(sm);
        int orow = r0 + quad * 4 + r;
        if (orow < N) {
            if (fx) {
                ((float*)out)[(long long)orow * 32 + m]      = v0 - lse;
                ((float*)out)[(long long)orow * 32 + 16 + m] = v1 - lse;
            } else {
                ((bf16*)out)[(long long)orow * 32 + m]      = __float2bfloat16(v0 - lse);
                ((bf16*)out)[(long long)orow * 32 + 16 + m] = __float2bfloat16(v1 - lse);
            }
        }
    }
}

extern "C" void kernel_launch(void* const* d_in, const int* in_sizes, int n_in,
                              void* d_out, int out_size, void* d_ws, size_t ws_size,
                              hipStream_t stream) {
    const void* x  = d_in[0];
    const int*  ei = (const int*)d_in[1];
    const void* W1 = d_in[2];
    const void* b1 = d_in[3];
    const void* W2 = d_in[4];
    const void* b2 = d_in[5];
    const void* Wl = d_in[6];
    const void* bl = d_in[7];

    int N = in_sizes[0] / 128;
    int E = in_sizes[1] / 2;

    int shift = 9;
    while (((N + (1 << shift) - 1) >> shift) > 256 && shift < 10) shift++;
    int NB = (N + (1 << shift) - 1) >> shift;   // 196 at N=100k

    // ws layout (4B units):
    // [flags 16 | bucketCount 256 | bucketBase 272 | bcursor 256 | dinv N | rowptr N+16 |
    //  Bp1 4096 | Bp2 1024 | Bp3 3584 | csr_src E | xb N*64 |
    //  A N*64 (ebuf int2 E<=N*32; then h1g f16 N*32; later h2g f16 N*16 + h2b N*16) | h1b N*32]
    int* ip      = (int*)d_ws;
    int* flags   = ip;
    int* bucketCount = ip + 16;
    int* bucketBase  = bucketCount + 256;
    int* bcursor     = bucketBase + 272;
    float* dinv  = (float*)(bcursor + 256);
    int* rowptr  = (int*)(dinv + N);
    bf16* Bp1    = (bf16*)(rowptr + N + 16);
    bf16* Bp2    = (bf16*)((int*)Bp1 + 4096);
    bf16* Bp3    = (bf16*)((int*)Bp2 + 1024);
    int* csr_src = (int*)Bp3 + 3584;
    short* xb    = (short*)(csr_src + E);                 // N*64 ints
    int*   Ai    = (int*)xb + (size_t)N * 64;             // region A: N*64 ints
    int2*  ebuf  = (int2*)Ai;                             // E*2 ints (dead before gemm1)
    __half* h1g  = (__half*)Ai;                           // N*64 halves = N*32 ints
    __half* h2g  = (__half*)Ai;                           // alias (h1g dead after gather1), N*16 ints
    unsigned int* h2b = (unsigned int*)(Ai + (size_t)N * 48);  // N*16 uints
    unsigned int* h1b = (unsigned int*)(Ai + (size_t)N * 64);  // N*32 uints

    // zero flags + bucketCount
    hipMemsetAsync(ip, 0, (16 + 256) * sizeof(int), stream);

    sniff_kernel<<<3, 256, 0, stream>>>(x, W1, ei, E, flags);

    int nchunk = (E + 4095) / 4096;
    bhist_kernel<<<nchunk, 256, 0, stream>>>(ei, E, flags, shift, NB, bucketCount);
    bscan_kernel<<<1, 256, 0, stream>>>(bucketCount, NB, bucketBase, bcursor, E);
    bpart_kernel<<<nchunk, 256, 0, stream>>>(ei, E, flags, shift, NB, bcursor, ebuf);
    bbuild_kernel<<<NB, 256, 0, stream>>>(ebuf, bucketBase, shift, N, E, rowptr, dinv, csr_src);

    repack_kernel<<<3, 256, 0, stream>>>(W1, W2, Wl, flags, Bp1, Bp2, Bp3);

    long long total8 = (long long)N * 16;   // groups of 8 elements of x
    cvt_x_kernel<<<(int)((total8 + 255) / 256), 256, 0, stream>>>(x, flags, xb, total8);

    gemm1_mfma_kernel<<<(N + 127) / 128, 256, 0, stream>>>(xb, Bp1, dinv, h1g, N);
    gather1_kernel<<<(N + 7) / 8, 256, 0, stream>>>((const unsigned int*)h1g, dinv, rowptr, csr_src,
                                                    b1, flags, h1b, N);
    gemm2_mfma_kernel<<<(N + 63) / 64, 256, 0, stream>>>((const short*)h1b, Bp2, dinv, h2g, N);
    gather2_kernel<<<(N + 7) / 8, 256, 0, stream>>>((const unsigned int*)h2g, dinv, rowptr, csr_src,
                                                    b2, flags, h2b, N);
    final_mfma_kernel<<<(N + 63) / 64, 256, 0, stream>>>(xb, (const short*)h1b, (const short*)h2b,
                                                         Bp3, bl, flags, d_out, N);
}

// Round 5
// 310.050 us; speedup vs baseline: 1.0646x; 1.0646x over previous
//
#include <hip/hip_runtime.h>
#include <hip/hip_bf16.h>
#include <hip/hip_fp16.h>

typedef __hip_bfloat16 bf16;
typedef __attribute__((ext_vector_type(8))) short short8;   // 8 bf16 (4 VGPRs)
typedef __attribute__((ext_vector_type(4))) float f32x4;    // MFMA accumulator

#define MFMA16(a, b, c) __builtin_amdgcn_mfma_f32_16x16x32_bf16((a), (b), (c), 0, 0, 0)

// dual-mode float load: f32 ? float buffer : bf16 buffer (same element index)
static __device__ __forceinline__ float ldf(const void* p, long long i, bool f32) {
    return f32 ? ((const float*)p)[i] : __bfloat162float(((const bf16*)p)[i]);
}

static __device__ __forceinline__ short f2bs(float v) {
    union { bf16 h; short s; } u; u.h = __float2bfloat16(v); return u.s;
}

static __device__ __forceinline__ unsigned int pack_bf16x2(float a, float b) {
    return (unsigned int)(unsigned short)f2bs(a) | ((unsigned int)(unsigned short)f2bs(b) << 16);
}

// ---------------------------------------------------------------- encoding sniffer
// flags[0]: x is fp32?  flags[1]: weights are fp32?  flags[2]: edge_index is int64?
// MEASURED (R1 NaN-fail + R8 gating probe): this harness delivers x=fp32, W=fp32, out=fp32.
__global__ __launch_bounds__(256, 4)
void sniff_kernel(const void* __restrict__ x, const void* __restrict__ w,
                  const int* __restrict__ ei, int E, int* __restrict__ flags) {
    __shared__ int cnt;
    if (threadIdx.x == 0) cnt = 0;
    __syncthreads();
    if (blockIdx.x < 2) {
        const unsigned short* u = (const unsigned short*)(blockIdx.x == 0 ? x : w);
        int bad = 0;
        for (int i = threadIdx.x; i < 4096; i += 256) {
            unsigned e = (u[i] >> 7) & 0xFF;
            if (e >= 0xA0) bad++;
        }
        atomicAdd(&cnt, bad);
        __syncthreads();
        if (threadIdx.x == 0) flags[blockIdx.x] = (cnt > 16) ? 1 : 0;
    } else {
        int nz = 0;
        for (int i = threadIdx.x; i < 1024; i += 256)
            if (ei[2 * i + 1] != 0) nz++;
        atomicAdd(&cnt, nz);
        __syncthreads();
        if (threadIdx.x == 0) flags[2] = (cnt == 0) ? 1 : 0;
    }
}

static __device__ __forceinline__ int ld_src(const int* ei, int E, int e, bool i64) {
    return i64 ? ei[2 * e] : ei[e];
}
static __device__ __forceinline__ int ld_dst(const int* ei, int E, int e, bool i64) {
    return i64 ? ei[2 * (E + e)] : ei[E + e];
}

// ---------------------------------------------------------------- bucket CSR build
// shift=9: bucket b owns dst in [b*512, (b+1)*512). NB = ceil(N/512) <= 256.

// Pass A: global bucket histogram (LDS hist per block, 1 global add per bucket)
__global__ __launch_bounds__(256, 4)
void bhist_kernel(const int* __restrict__ ei, int E, const int* __restrict__ flags,
                  int shift, int NB, int* __restrict__ bucketCount) {
    __shared__ int h[256];
    for (int i = threadIdx.x; i < 256; i += 256) h[i] = 0;
    __syncthreads();
    bool i64 = flags[2] != 0;
    int base = blockIdx.x * 4096;
    for (int i = 0; i < 16; i++) {
        int e = base + i * 256 + threadIdx.x;
        if (e < E) atomicAdd(&h[ld_dst(ei, E, e, i64) >> shift], 1);
    }
    __syncthreads();
    for (int i = threadIdx.x; i < NB; i += 256)
        if (h[i]) atomicAdd(&bucketCount[i], h[i]);
}

// Pass B scan: bucketBase = exclusive scan; bcursor seeded with bases
__global__ __launch_bounds__(256, 4)
void bscan_kernel(const int* __restrict__ bucketCount, int NB,
                  int* __restrict__ bucketBase, int* __restrict__ bcursor, int E) {
    __shared__ int bs[256];
    int v = ((int)threadIdx.x < NB) ? bucketCount[threadIdx.x] : 0;
    bs[threadIdx.x] = v;
    __syncthreads();
    for (int off = 1; off < 256; off <<= 1) {
        int t = ((int)threadIdx.x >= off) ? bs[threadIdx.x - off] : 0;
        __syncthreads();
        bs[threadIdx.x] += t;
        __syncthreads();
    }
    int excl = bs[threadIdx.x] - v;
    if ((int)threadIdx.x < NB) { bucketBase[threadIdx.x] = excl; bcursor[threadIdx.x] = excl; }
    if (threadIdx.x == 0) bucketBase[NB] = E;
}

// Pass C: partition edges into bucket-contiguous ebuf (int2: x=src, y=dst)
// 4096-edge chunk cached in 32KB LDS during sweep 1 — kills the second
// 25.6MB read of ei.  (kept from R4 — independent win)
__global__ __launch_bounds__(256, 4)
void bpart_kernel(const int* __restrict__ ei, int E, const int* __restrict__ flags,
                  int shift, int NB, int* __restrict__ bcursor, int2* __restrict__ ebuf) {
    __shared__ int h[256];
    __shared__ int gofs[256];
    __shared__ int2 se[4096];    // 32KB edge cache
    for (int i = threadIdx.x; i < 256; i += 256) h[i] = 0;
    __syncthreads();
    bool i64 = flags[2] != 0;
    int base = blockIdx.x * 4096;
    // sweep 1: local histogram + LDS cache
    for (int i = 0; i < 16; i++) {
        int e = base + i * 256 + threadIdx.x;
        if (e < E) {
            int s = ld_src(ei, E, e, i64), d = ld_dst(ei, E, e, i64);
            se[i * 256 + threadIdx.x] = make_int2(s, d);
            atomicAdd(&h[d >> shift], 1);
        }
    }
    __syncthreads();
    // claim contiguous global ranges (1 atomic per bucket per block)
    if ((int)threadIdx.x < NB) {
        int c = h[threadIdx.x];
        gofs[threadIdx.x] = c ? atomicAdd(&bcursor[threadIdx.x], c) : 0;
    }
    __syncthreads();
    for (int i = threadIdx.x; i < 256; i += 256) h[i] = 0;
    __syncthreads();
    // sweep 2: write edges into claimed dense runs (from LDS)
    for (int i = 0; i < 16; i++) {
        int e = base + i * 256 + threadIdx.x;
        if (e < E) {
            int2 v = se[i * 256 + threadIdx.x];
            int b = v.y >> shift;
            int p = atomicAdd(&h[b], 1);
            ebuf[gofs[b] + p] = v;
        }
    }
}

// Pass D: one block per bucket — local count, scan, rowptr+dinv write, csr fill.
// All csr writes land in one block's ~32KB window (single XCD L2; no line ping-pong).
__global__ __launch_bounds__(256, 2)
void bbuild_kernel(const int2* __restrict__ ebuf, const int* __restrict__ bucketBase,
                   int shift, int N, int E, int* __restrict__ rowptr,
                   float* __restrict__ dinv, int* __restrict__ csr_src) {
    __shared__ int cnt[1024];
    __shared__ int exc[1024];
    __shared__ int bs[256];
    int b = blockIdx.x;
    int nodeBase = b << shift;
    int width = 1 << shift;
    int nn = N - nodeBase; if (nn > width) nn = width;
    int beg = bucketBase[b], end = bucketBase[b + 1];
    for (int i = threadIdx.x; i < width; i += 256) cnt[i] = 0;
    __syncthreads();
    for (int e = beg + threadIdx.x; e < end; e += 256)
        atomicAdd(&cnt[ebuf[e].y - nodeBase], 1);
    __syncthreads();
    // exclusive scan of cnt[0..width)
    int per = width / 256;          // 2 at shift=9
    int s = 0;
    int base4 = threadIdx.x * per;
    for (int i = 0; i < per; i++) s += cnt[base4 + i];
    bs[threadIdx.x] = s;
    __syncthreads();
    for (int off = 1; off < 256; off <<= 1) {
        int t = ((int)threadIdx.x >= off) ? bs[threadIdx.x - off] : 0;
        __syncthreads();
        bs[threadIdx.x] += t;
        __syncthreads();
    }
    int run = bs[threadIdx.x] - s;
    for (int i = 0; i < per; i++) { exc[base4 + i] = run; run += cnt[base4 + i]; }
    __syncthreads();
    // rowptr + dinv (coalesced)
    for (int i = threadIdx.x; i < nn; i += 256) {
        int node = nodeBase + i;
        rowptr[node] = beg + exc[i];
        dinv[node] = rsqrtf((float)cnt[i] + 1.0f);
    }
    __syncthreads();
    for (int i = threadIdx.x; i < width; i += 256) cnt[i] = 0;
    __syncthreads();
    // csr fill within local window
    for (int e = beg + threadIdx.x; e < end; e += 256) {
        int2 v = ebuf[e];
        int l = v.y - nodeBase;
        int p = atomicAdd(&cnt[l], 1);
        csr_src[beg + exc[l] + p] = v.x;
    }
    if (b == 0 && threadIdx.x == 0) rowptr[N] = E;
}

// ---------------------------------------------------------------- weight -> MFMA B-fragment packs
// frag f = kstep*ntiles + ntile; slot s = f*64 + lane; element j (0..7):
//   W[kstep*32 + (lane>>4)*8 + j][ntile*16 + (lane&15)]  (fw-aware fp32/bf16 read)
__global__ __launch_bounds__(256, 4)
void repack_kernel(const void* __restrict__ W1, const void* __restrict__ W2,
                   const void* __restrict__ Wl, const int* __restrict__ flags,
                   bf16* __restrict__ Bp1, bf16* __restrict__ Bp2, bf16* __restrict__ Bp3) {
    bool fw = flags[1] != 0;
    const void* W; bf16* Bp; int ntiles, nc, nfrag;
    if (blockIdx.x == 0)      { W = W1; Bp = Bp1; ntiles = 4; nc = 64; nfrag = 16; }
    else if (blockIdx.x == 1) { W = W2; Bp = Bp2; ntiles = 2; nc = 32; nfrag = 4;  }
    else                      { W = Wl; Bp = Bp3; ntiles = 2; nc = 32; nfrag = 14; }
    for (int s = threadIdx.x; s < nfrag * 64; s += 256) {
        int f = s >> 6, lane = s & 63;
        int kstep = f / ntiles, ntile = f % ntiles;
        int n = ntile * 16 + (lane & 15);
        int kbase = kstep * 32 + (lane >> 4) * 8;
#pragma unroll
        for (int j = 0; j < 8; j++)
            Bp[s * 8 + j] = __float2bfloat16(ldf(W, (long long)(kbase + j) * nc + n, fw));
    }
}

// ---------------------------------------------------------------- x -> xb (bf16), both source dtypes
__global__ __launch_bounds__(256, 4)
void cvt_x_kernel(const void* __restrict__ x, const int* __restrict__ flags,
                  short* __restrict__ xb, long long total8) {
    long long i = (long long)blockIdx.x * 256 + threadIdx.x;
    if (i >= total8) return;
    bool fx = flags[0] != 0;
    short8 o;
    if (fx) {
        const float4* xf = (const float4*)x;
        float4 a = xf[i * 2], b = xf[i * 2 + 1];
        o[0] = f2bs(a.x); o[1] = f2bs(a.y); o[2] = f2bs(a.z); o[3] = f2bs(a.w);
        o[4] = f2bs(b.x); o[5] = f2bs(b.y); o[6] = f2bs(b.z); o[7] = f2bs(b.w);
    } else {
        o = ((const short8*)x)[i];
    }
    ((short8*)xb)[i] = o;
}

// ---------------------------------------------------------------- GEMM1 (MFMA): xb[N,128]@W1 -> h1g[N,64] f16 rows
// Epilogue scales row r by dinv[r] and stores f16 (rel err 2^-11, negligible vs
// the bf16 rounding already applied downstream).  128B rows halve the gather's
// L2-miss volume (the measured 3.7 TB/s wall is miss-volume-bound).
__global__ __launch_bounds__(256, 3)
void gemm1_mfma_kernel(const short* __restrict__ xb, const bf16* __restrict__ Bpack,
                       const float* __restrict__ dinv, __half* __restrict__ h1g, int N) {
    int lane = threadIdx.x & 63, wave = threadIdx.x >> 6;
    int m = lane & 15, quad = lane >> 4;
    int base = blockIdx.x * 128 + wave * 32;
    if (base >= N) return;
    const short8* bp = (const short8*)Bpack;
    short8 B[16];
#pragma unroll
    for (int i = 0; i < 16; i++) B[i] = bp[i * 64 + lane];
    if (base + 32 <= N) {
#pragma unroll
        for (int t = 0; t < 2; t++) {
            int r0 = base + t * 16;
            const short* xr = &xb[(long long)(r0 + m) * 128 + quad * 8];
            short8 A[4];
#pragma unroll
            for (int k = 0; k < 4; k++) A[k] = *(const short8*)(xr + k * 32);
            f32x4 acc[4];
#pragma unroll
            for (int nt = 0; nt < 4; nt++) acc[nt] = (f32x4){0.f, 0.f, 0.f, 0.f};
#pragma unroll
            for (int k = 0; k < 4; k++) {
#pragma unroll
                for (int nt = 0; nt < 4; nt++) acc[nt] = MFMA16(A[k], B[k * 4 + nt], acc[nt]);
            }
            // C/D: col = lane&15, row = quad*4 + r  [m89/m91]
            float dv[4];
#pragma unroll
            for (int r = 0; r < 4; r++) dv[r] = dinv[r0 + quad * 4 + r];
            __half* o = &h1g[(long long)(r0 + quad * 4) * 64 + m];
#pragma unroll
            for (int nt = 0; nt < 4; nt++) {
#pragma unroll
                for (int r = 0; r < 4; r++) o[(long long)r * 64 + nt * 16] = __float2half(acc[nt][r] * dv[r]);
            }
        }
    } else {
#pragma unroll
        for (int t = 0; t < 2; t++) {
            int r0 = base + t * 16;
            int row = r0 + m;
            short8 A[4];
#pragma unroll
            for (int k = 0; k < 4; k++) A[k] = (short8){0,0,0,0,0,0,0,0};
            if (row < N) {
                const short* xr = &xb[(long long)row * 128 + quad * 8];
#pragma unroll
                for (int k = 0; k < 4; k++) A[k] = *(const short8*)(xr + k * 32);
            }
            f32x4 acc[4];
#pragma unroll
            for (int nt = 0; nt < 4; nt++) acc[nt] = (f32x4){0.f, 0.f, 0.f, 0.f};
#pragma unroll
            for (int k = 0; k < 4; k++) {
#pragma unroll
                for (int nt = 0; nt < 4; nt++) acc[nt] = MFMA16(A[k], B[k * 4 + nt], acc[nt]);
            }
#pragma unroll
            for (int r = 0; r < 4; r++) {
                int orow = r0 + quad * 4 + r;
                if (orow < N) {
                    float dv = dinv[orow];
                    __half* o = &h1g[(long long)orow * 64 + m];
#pragma unroll
                    for (int nt = 0; nt < 4; nt++) o[nt * 16] = __float2half(acc[nt][r] * dv);
                }
            }
        }
    }
}

// ---------------------------------------------------------------- gather layer 1: one wave per node -> h1b (bf16 packed)
// R5: back to R3's one-node-per-wave (R4 pairing regressed: max(deg)-trip waste
// + occupancy drop).  New: loop split into UNMASKED full batches (consecutive
// uniform csr_src reads -> compiler merges into s_load_dwordx8/x16; plain adds,
// no mask VALU) + one masked tail batch.  32-edge deep path only where free.
__global__ __launch_bounds__(256, 8)
void gather1_kernel(const unsigned int* __restrict__ h1g, const float* __restrict__ dinv,
                    const int* __restrict__ rowptr, const int* __restrict__ csr_src,
                    const void* __restrict__ bptr, const int* __restrict__ flags,
                    unsigned int* __restrict__ h1b, int N) {
    bool fw = flags[1] != 0;
    int lane = threadIdx.x & 63;
    int c = lane & 31, hf = lane >> 5;
    int wv = __builtin_amdgcn_readfirstlane(threadIdx.x >> 6);
    int node = blockIdx.x * 4 + wv;
    if (node >= N) return;
    int beg = rowptr[node], end = rowptr[node + 1];
    const unsigned int* hL = h1g + c;
    float a0 = 0.f, a1 = 0.f;
    int p = beg;
    // 32-edge unmasked batches (16 row-loads in flight)
    for (; p + 32 <= end; p += 32) {
        unsigned int v[16];
#pragma unroll
        for (int u = 0; u < 16; u++) {
            int s0 = csr_src[p + 2 * u];       // uniform, consecutive -> merged s_load
            int s1 = csr_src[p + 2 * u + 1];
            int s = hf ? s1 : s0;
            v[u] = hL[(long long)s * 32];
        }
#pragma unroll
        for (int u = 0; u < 16; u++) {
            float2 f = __half22float2(*(const __half2*)&v[u]);
            a0 += f.x; a1 += f.y;
        }
    }
    // 16-edge unmasked batch
    for (; p + 16 <= end; p += 16) {
        unsigned int v[8];
#pragma unroll
        for (int u = 0; u < 8; u++) {
            int s0 = csr_src[p + 2 * u];
            int s1 = csr_src[p + 2 * u + 1];
            int s = hf ? s1 : s0;
            v[u] = hL[(long long)s * 32];
        }
#pragma unroll
        for (int u = 0; u < 8; u++) {
            float2 f = __half22float2(*(const __half2*)&v[u]);
            a0 += f.x; a1 += f.y;
        }
    }
    // masked tail (<16 edges)
    if (p < end) {
        unsigned int v[8]; float m[8];
#pragma unroll
        for (int u = 0; u < 8; u++) {
            int i0 = p + 2 * u, i1 = i0 + 1;
            int s0 = csr_src[(i0 < end) ? i0 : beg];
            int s1 = csr_src[(i1 < end) ? i1 : beg];
            int s = hf ? s1 : s0;
            m[u] = hf ? ((i1 < end) ? 1.f : 0.f) : ((i0 < end) ? 1.f : 0.f);
            v[u] = hL[(long long)s * 32];
        }
#pragma unroll
        for (int u = 0; u < 8; u++) {
            float2 f = __half22float2(*(const __half2*)&v[u]);
            a0 = fmaf(f.x, m[u], a0);
            a1 = fmaf(f.y, m[u], a1);
        }
    }
    a0 += __shfl_xor(a0, 32);
    a1 += __shfl_xor(a1, 32);
    if (hf == 0) {
        unsigned int gsv = h1g[(long long)node * 32 + c];
        float2 gs = __half22float2(*(const __half2*)&gsv);
        float dvd = dinv[node];
        float o0 = dvd * (a0 + gs.x) + ldf(bptr, 2 * c, fw);
        float o1 = dvd * (a1 + gs.y) + ldf(bptr, 2 * c + 1, fw);
        h1b[(long long)node * 32 + c] = pack_bf16x2(fmaxf(o0, 0.f), fmaxf(o1, 0.f));
    }
}

// ---------------------------------------------------------------- GEMM2 (MFMA): h1b[N,64]@W2 -> h2g[N,32] f16 rows (dinv-scaled)
__global__ __launch_bounds__(256, 4)
void gemm2_mfma_kernel(const short* __restrict__ h1b, const bf16* __restrict__ Bpack,
                       const float* __restrict__ dinv, __half* __restrict__ h2g, int N) {
    int lane = threadIdx.x & 63, wave = threadIdx.x >> 6;
    int m = lane & 15, quad = lane >> 4;
    int r0 = blockIdx.x * 64 + wave * 16;
    if (r0 >= N) return;
    const short8* bp = (const short8*)Bpack;
    short8 B[4];
#pragma unroll
    for (int i = 0; i < 4; i++) B[i] = bp[i * 64 + lane];
    f32x4 acc0 = {0.f,0.f,0.f,0.f}, acc1 = {0.f,0.f,0.f,0.f};
    if (r0 + 16 <= N) {
        const short* xr = &h1b[(long long)(r0 + m) * 64 + quad * 8];
#pragma unroll
        for (int k = 0; k < 2; k++) {
            short8 A = *(const short8*)(xr + k * 32);
            acc0 = MFMA16(A, B[k * 2 + 0], acc0);
            acc1 = MFMA16(A, B[k * 2 + 1], acc1);
        }
        float dv[4];
#pragma unroll
        for (int r = 0; r < 4; r++) dv[r] = dinv[r0 + quad * 4 + r];
        __half* o = &h2g[(long long)(r0 + quad * 4) * 32 + m];
#pragma unroll
        for (int r = 0; r < 4; r++) {
            o[(long long)r * 32]      = __float2half(acc0[r] * dv[r]);
            o[(long long)r * 32 + 16] = __float2half(acc1[r] * dv[r]);
        }
    } else {
        int row = r0 + m;
#pragma unroll
        for (int k = 0; k < 2; k++) {
            short8 A = {0,0,0,0,0,0,0,0};
            if (row < N) A = *(const short8*)&h1b[(long long)row * 64 + k * 32 + quad * 8];
            acc0 = MFMA16(A, B[k * 2 + 0], acc0);
            acc1 = MFMA16(A, B[k * 2 + 1], acc1);
        }
#pragma unroll
        for (int r = 0; r < 4; r++) {
            int orow = r0 + quad * 4 + r;
            if (orow < N) {
                float dv = dinv[orow];
                h2g[(long long)orow * 32 + m]      = __float2half(acc0[r] * dv);
                h2g[(long long)orow * 32 + 16 + m] = __float2half(acc1[r] * dv);
            }
        }
    }
}

// ---------------------------------------------------------------- gather layer 2: h2g (f16x2, 64B rows) -> h2b (bf16 packed)
// R5: one node per wave (revert pairing), same unmasked-batch split as gather1.
// 16-lane group per edge, 4 edges per load, 16 edges per batch.
__global__ __launch_bounds__(256, 8)
void gather2_kernel(const unsigned int* __restrict__ h2g, const float* __restrict__ dinv,
                    const int* __restrict__ rowptr, const int* __restrict__ csr_src,
                    const void* __restrict__ bptr, const int* __restrict__ flags,
                    unsigned int* __restrict__ h2b, int N) {
    bool fw = flags[1] != 0;
    int lane = threadIdx.x & 63;
    int c = lane & 15, sub = lane >> 4;
    int wv = __builtin_amdgcn_readfirstlane(threadIdx.x >> 6);
    int node = blockIdx.x * 4 + wv;
    if (node >= N) return;
    int beg = rowptr[node], end = rowptr[node + 1];
    const unsigned int* hL = h2g + c;
    float a0 = 0.f, a1 = 0.f;
    int p = beg;
    // 32-edge unmasked batches (8 loads in flight)
    for (; p + 32 <= end; p += 32) {
        unsigned int v[8];
#pragma unroll
        for (int u = 0; u < 8; u++) {
            int i0 = p + 4 * u;
            int sa0 = csr_src[i0], sa1 = csr_src[i0 + 1];
            int sa2 = csr_src[i0 + 2], sa3 = csr_src[i0 + 3];
            int sA = (sub & 1) ? sa1 : sa0;
            int sB = (sub & 1) ? sa3 : sa2;
            int s  = (sub & 2) ? sB : sA;
            v[u] = hL[(long long)s * 16];
        }
#pragma unroll
        for (int u = 0; u < 8; u++) {
            float2 f = __half22float2(*(const __half2*)&v[u]);
            a0 += f.x; a1 += f.y;
        }
    }
    // 16-edge unmasked batch
    for (; p + 16 <= end; p += 16) {
        unsigned int v[4];
#pragma unroll
        for (int u = 0; u < 4; u++) {
            int i0 = p + 4 * u;
            int sa0 = csr_src[i0], sa1 = csr_src[i0 + 1];
            int sa2 = csr_src[i0 + 2], sa3 = csr_src[i0 + 3];
            int sA = (sub & 1) ? sa1 : sa0;
            int sB = (sub & 1) ? sa3 : sa2;
            int s  = (sub & 2) ? sB : sA;
            v[u] = hL[(long long)s * 16];
        }
#pragma unroll
        for (int u = 0; u < 4; u++) {
            float2 f = __half22float2(*(const __half2*)&v[u]);
            a0 += f.x; a1 += f.y;
        }
    }
    // masked tail (<16 edges)
    if (p < end) {
        unsigned int v[4]; float m[4];
#pragma unroll
        for (int u = 0; u < 4; u++) {
            int i0 = p + 4 * u;
            int sa0 = csr_src[(i0     < end) ? i0     : beg];
            int sa1 = csr_src[(i0 + 1 < end) ? i0 + 1 : beg];
            int sa2 = csr_src[(i0 + 2 < end) ? i0 + 2 : beg];
            int sa3 = csr_src[(i0 + 3 < end) ? i0 + 3 : beg];
            int sA = (sub & 1) ? sa1 : sa0;
            int sB = (sub & 1) ? sa3 : sa2;
            int s  = (sub & 2) ? sB : sA;
            float ma = (sub & 1) ? ((i0 + 1 < end) ? 1.f : 0.f) : ((i0 < end) ? 1.f : 0.f);
            float mb = (sub & 1) ? ((i0 + 3 < end) ? 1.f : 0.f) : ((i0 + 2 < end) ? 1.f : 0.f);
            m[u] = (sub & 2) ? mb : ma;
            v[u] = hL[(long long)s * 16];
        }
#pragma unroll
        for (int u = 0; u < 4; u++) {
            float2 f = __half22float2(*(const __half2*)&v[u]);
            a0 = fmaf(f.x, m[u], a0);
            a1 = fmaf(f.y, m[u], a1);
        }
    }
    a0 += __shfl_xor(a0, 16); a1 += __shfl_xor(a1, 16);
    a0 += __shfl_xor(a0, 32); a1 += __shfl_xor(a1, 32);
    if (sub == 0) {
        unsigned int gsv = h2g[(long long)node * 16 + c];
        float2 gs = __half22float2(*(const __half2*)&gsv);
        float dvd = dinv[node];
        float o0 = dvd * (a0 + gs.x) + ldf(bptr, 2 * c, fw);
        float o1 = dvd * (a1 + gs.y) + ldf(bptr, 2 * c + 1, fw);
        h2b[(long long)node * 16 + c] = pack_bf16x2(o0, o1);
    }
}

// ---------------------------------------------------------------- final (MFMA): [xb|h1b|h2b]@Wl + bl -> log_softmax
__global__ __launch_bounds__(256, 2)
void final_mfma_kernel(const short* __restrict__ xb, const short* __restrict__ h1b,
                       const short* __restrict__ h2b, const bf16* __restrict__ Bpack,
                       const void* __restrict__ bl, const int* __restrict__ flags,
                       void* __restrict__ out, int N) {
    bool fw = flags[1] != 0, fx = flags[0] != 0;
    int lane = threadIdx.x & 63, wave = threadIdx.x >> 6;
    int m = lane & 15, quad = lane >> 4;
    int r0 = blockIdx.x * 64 + wave * 16;
    if (r0 >= N) return;
    const short8* bp = (const short8*)Bpack;
    short8 B[14];
#pragma unroll
    for (int i = 0; i < 14; i++) B[i] = bp[i * 64 + lane];
    f32x4 acc0 = {0.f,0.f,0.f,0.f}, acc1 = {0.f,0.f,0.f,0.f};
    bool full = (r0 + 16 <= N);
    int row = r0 + m;
    bool rowok = full || (row < N);
#pragma unroll
    for (int s = 0; s < 7; s++) {
        short8 A = {0,0,0,0,0,0,0,0};
        if (rowok) {
            const short* p;
            if (s < 4)      p = &xb [(long long)row * 128 + s * 32 + quad * 8];
            else if (s < 6) p = &h1b[(long long)row * 64 + (s - 4) * 32 + quad * 8];
            else            p = &h2b[(long long)row * 32 + quad * 8];
            A = *(const short8*)p;
        }
        acc0 = MFMA16(A, B[s * 2 + 0], acc0);
        acc1 = MFMA16(A, B[s * 2 + 1], acc1);
    }
    float bl0 = ldf(bl, m, fw), bl1 = ldf(bl, m + 16, fw);
#pragma unroll
    for (int r = 0; r < 4; r++) {
        float v0 = acc0[r] + bl0, v1 = acc1[r] + bl1;
        float mx = fmaxf(v0, v1);
#pragma unroll
        for (int o = 8; o > 0; o >>= 1) mx = fmaxf(mx, __shfl_xor(mx, o));
        float sm = __expf(v0 - mx) + __expf(v1 - mx);
#pragma unroll
        for (int o = 8; o > 0; o >>= 1) sm += __shfl_xor(sm, o);
        float lse = mx + __logf(sm);
        int orow = r0 + quad * 4 + r;
        if (orow < N) {
            if (fx) {
                ((float*)out)[(long long)orow * 32 + m]      = v0 - lse;
                ((float*)out)[(long long)orow * 32 + 16 + m] = v1 - lse;
            } else {
                ((bf16*)out)[(long long)orow * 32 + m]      = __float2bfloat16(v0 - lse);
                ((bf16*)out)[(long long)orow * 32 + 16 + m] = __float2bfloat16(v1 - lse);
            }
        }
    }
}

extern "C" void kernel_launch(void* const* d_in, const int* in_sizes, int n_in,
                              void* d_out, int out_size, void* d_ws, size_t ws_size,
                              hipStream_t stream) {
    const void* x  = d_in[0];
    const int*  ei = (const int*)d_in[1];
    const void* W1 = d_in[2];
    const void* b1 = d_in[3];
    const void* W2 = d_in[4];
    const void* b2 = d_in[5];
    const void* Wl = d_in[6];
    const void* bl = d_in[7];

    int N = in_sizes[0] / 128;
    int E = in_sizes[1] / 2;

    int shift = 9;
    while (((N + (1 << shift) - 1) >> shift) > 256 && shift < 10) shift++;
    int NB = (N + (1 << shift) - 1) >> shift;   // 196 at N=100k

    // ws layout (4B units):
    // [flags 16 | bucketCount 256 | bucketBase 272 | bcursor 256 | dinv N | rowptr N+16 |
    //  Bp1 4096 | Bp2 1024 | Bp3 3584 | csr_src E | xb N*64 |
    //  A N*64 (ebuf int2 E<=N*32; then h1g f16 N*32; later h2g f16 N*16 + h2b N*16) | h1b N*32]
    int* ip      = (int*)d_ws;
    int* flags   = ip;
    int* bucketCount = ip + 16;
    int* bucketBase  = bucketCount + 256;
    int* bcursor     = bucketBase + 272;
    float* dinv  = (float*)(bcursor + 256);
    int* rowptr  = (int*)(dinv + N);
    bf16* Bp1    = (bf16*)(rowptr + N + 16);
    bf16* Bp2    = (bf16*)((int*)Bp1 + 4096);
    bf16* Bp3    = (bf16*)((int*)Bp2 + 1024);
    int* csr_src = (int*)Bp3 + 3584;
    short* xb    = (short*)(csr_src + E);                 // N*64 ints
    int*   Ai    = (int*)xb + (size_t)N * 64;             // region A: N*64 ints
    int2*  ebuf  = (int2*)Ai;                             // E*2 ints (dead before gemm1)
    __half* h1g  = (__half*)Ai;                           // N*64 halves = N*32 ints
    __half* h2g  = (__half*)Ai;                           // alias (h1g dead after gather1), N*16 ints
    unsigned int* h2b = (unsigned int*)(Ai + (size_t)N * 48);  // N*16 uints
    unsigned int* h1b = (unsigned int*)(Ai + (size_t)N * 64);  // N*32 uints

    // zero flags + bucketCount
    hipMemsetAsync(ip, 0, (16 + 256) * sizeof(int), stream);

    sniff_kernel<<<3, 256, 0, stream>>>(x, W1, ei, E, flags);

    int nchunk = (E + 4095) / 4096;
    bhist_kernel<<<nchunk, 256, 0, stream>>>(ei, E, flags, shift, NB, bucketCount);
    bscan_kernel<<<1, 256, 0, stream>>>(bucketCount, NB, bucketBase, bcursor, E);
    bpart_kernel<<<nchunk, 256, 0, stream>>>(ei, E, flags, shift, NB, bcursor, ebuf);
    bbuild_kernel<<<NB, 256, 0, stream>>>(ebuf, bucketBase, shift, N, E, rowptr, dinv, csr_src);

    repack_kernel<<<3, 256, 0, stream>>>(W1, W2, Wl, flags, Bp1, Bp2, Bp3);

    long long total8 = (long long)N * 16;   // groups of 8 elements of x
    cvt_x_kernel<<<(int)((total8 + 255) / 256), 256, 0, stream>>>(x, flags, xb, total8);

    gemm1_mfma_kernel<<<(N + 127) / 128, 256, 0, stream>>>(xb, Bp1, dinv, h1g, N);
    gather1_kernel<<<(N + 3) / 4, 256, 0, stream>>>((const unsigned int*)h1g, dinv, rowptr, csr_src,
                                                    b1, flags, h1b, N);
    gemm2_mfma_kernel<<<(N + 63) / 64, 256, 0, stream>>>((const short*)h1b, Bp2, dinv, h2g, N);
    gather2_kernel<<<(N + 3) / 4, 256, 0, stream>>>((const unsigned int*)h2g, dinv, rowptr, csr_src,
                                                    b2, flags, h2b, N);
    final_mfma_kernel<<<(N + 63) / 64, 256, 0, stream>>>(xb, (const short*)h1b, (const short*)h2b,
                                                         Bp3, bl, flags, d_out, N);
}

// Round 6
// 293.167 us; speedup vs baseline: 1.1259x; 1.0576x over previous
//
#include <hip/hip_runtime.h>
#include <hip/hip_bf16.h>
#include <hip/hip_fp16.h>

typedef __hip_bfloat16 bf16;
typedef __attribute__((ext_vector_type(8))) short short8;   // 8 bf16 (4 VGPRs)
typedef __attribute__((ext_vector_type(4))) float f32x4;    // MFMA accumulator

#define MFMA16(a, b, c) __builtin_amdgcn_mfma_f32_16x16x32_bf16((a), (b), (c), 0, 0, 0)

// dual-mode float load: f32 ? float buffer : bf16 buffer (same element index)
static __device__ __forceinline__ float ldf(const void* p, long long i, bool f32) {
    return f32 ? ((const float*)p)[i] : __bfloat162float(((const bf16*)p)[i]);
}

static __device__ __forceinline__ short f2bs(float v) {
    union { bf16 h; short s; } u; u.h = __float2bfloat16(v); return u.s;
}

static __device__ __forceinline__ unsigned int pack_bf16x2(float a, float b) {
    return (unsigned int)(unsigned short)f2bs(a) | ((unsigned int)(unsigned short)f2bs(b) << 16);
}

// ---------------------------------------------------------------- encoding sniffer
// flags[0]: x is fp32?  flags[1]: weights are fp32?  flags[2]: edge_index is int64?
// MEASURED (R1 NaN-fail + R8 gating probe): this harness delivers x=fp32, W=fp32, out=fp32.
__global__ __launch_bounds__(256, 4)
void sniff_kernel(const void* __restrict__ x, const void* __restrict__ w,
                  const int* __restrict__ ei, int E, int* __restrict__ flags) {
    __shared__ int cnt;
    if (threadIdx.x == 0) cnt = 0;
    __syncthreads();
    if (blockIdx.x < 2) {
        const unsigned short* u = (const unsigned short*)(blockIdx.x == 0 ? x : w);
        int bad = 0;
        for (int i = threadIdx.x; i < 4096; i += 256) {
            unsigned e = (u[i] >> 7) & 0xFF;
            if (e >= 0xA0) bad++;
        }
        atomicAdd(&cnt, bad);
        __syncthreads();
        if (threadIdx.x == 0) flags[blockIdx.x] = (cnt > 16) ? 1 : 0;
    } else {
        int nz = 0;
        for (int i = threadIdx.x; i < 1024; i += 256)
            if (ei[2 * i + 1] != 0) nz++;
        atomicAdd(&cnt, nz);
        __syncthreads();
        if (threadIdx.x == 0) flags[2] = (cnt == 0) ? 1 : 0;
    }
}

static __device__ __forceinline__ int ld_src(const int* ei, int E, int e, bool i64) {
    return i64 ? ei[2 * e] : ei[e];
}
static __device__ __forceinline__ int ld_dst(const int* ei, int E, int e, bool i64) {
    return i64 ? ei[2 * (E + e)] : ei[E + e];
}

// ---------------------------------------------------------------- bucket CSR build
// shift=9: bucket b owns dst in [b*512, (b+1)*512). NB = ceil(N/512) <= 256.

// Pass A: global bucket histogram (LDS hist per block, 1 global add per bucket)
__global__ __launch_bounds__(256, 4)
void bhist_kernel(const int* __restrict__ ei, int E, const int* __restrict__ flags,
                  int shift, int NB, int* __restrict__ bucketCount) {
    __shared__ int h[256];
    for (int i = threadIdx.x; i < 256; i += 256) h[i] = 0;
    __syncthreads();
    bool i64 = flags[2] != 0;
    int base = blockIdx.x * 4096;
    for (int i = 0; i < 16; i++) {
        int e = base + i * 256 + threadIdx.x;
        if (e < E) atomicAdd(&h[ld_dst(ei, E, e, i64) >> shift], 1);
    }
    __syncthreads();
    for (int i = threadIdx.x; i < NB; i += 256)
        if (h[i]) atomicAdd(&bucketCount[i], h[i]);
}

// Pass B scan: bucketBase = exclusive scan; bcursor seeded with bases
__global__ __launch_bounds__(256, 4)
void bscan_kernel(const int* __restrict__ bucketCount, int NB,
                  int* __restrict__ bucketBase, int* __restrict__ bcursor, int E) {
    __shared__ int bs[256];
    int v = ((int)threadIdx.x < NB) ? bucketCount[threadIdx.x] : 0;
    bs[threadIdx.x] = v;
    __syncthreads();
    for (int off = 1; off < 256; off <<= 1) {
        int t = ((int)threadIdx.x >= off) ? bs[threadIdx.x - off] : 0;
        __syncthreads();
        bs[threadIdx.x] += t;
        __syncthreads();
    }
    int excl = bs[threadIdx.x] - v;
    if ((int)threadIdx.x < NB) { bucketBase[threadIdx.x] = excl; bcursor[threadIdx.x] = excl; }
    if (threadIdx.x == 0) bucketBase[NB] = E;
}

// Pass C: partition edges into bucket-contiguous ebuf (int2: x=src, y=dst)
// 4096-edge chunk cached in 32KB LDS during sweep 1 — kills the second
// 25.6MB read of ei.  (kept from R4 — independent win)
__global__ __launch_bounds__(256, 4)
void bpart_kernel(const int* __restrict__ ei, int E, const int* __restrict__ flags,
                  int shift, int NB, int* __restrict__ bcursor, int2* __restrict__ ebuf) {
    __shared__ int h[256];
    __shared__ int gofs[256];
    __shared__ int2 se[4096];    // 32KB edge cache
    for (int i = threadIdx.x; i < 256; i += 256) h[i] = 0;
    __syncthreads();
    bool i64 = flags[2] != 0;
    int base = blockIdx.x * 4096;
    // sweep 1: local histogram + LDS cache
    for (int i = 0; i < 16; i++) {
        int e = base + i * 256 + threadIdx.x;
        if (e < E) {
            int s = ld_src(ei, E, e, i64), d = ld_dst(ei, E, e, i64);
            se[i * 256 + threadIdx.x] = make_int2(s, d);
            atomicAdd(&h[d >> shift], 1);
        }
    }
    __syncthreads();
    // claim contiguous global ranges (1 atomic per bucket per block)
    if ((int)threadIdx.x < NB) {
        int c = h[threadIdx.x];
        gofs[threadIdx.x] = c ? atomicAdd(&bcursor[threadIdx.x], c) : 0;
    }
    __syncthreads();
    for (int i = threadIdx.x; i < 256; i += 256) h[i] = 0;
    __syncthreads();
    // sweep 2: write edges into claimed dense runs (from LDS)
    for (int i = 0; i < 16; i++) {
        int e = base + i * 256 + threadIdx.x;
        if (e < E) {
            int2 v = se[i * 256 + threadIdx.x];
            int b = v.y >> shift;
            int p = atomicAdd(&h[b], 1);
            ebuf[gofs[b] + p] = v;
        }
    }
}

// Pass D: one block per bucket — local count, scan, rowptr+dinv write, csr fill.
// All csr writes land in one block's ~32KB window (single XCD L2; no line ping-pong).
__global__ __launch_bounds__(256, 2)
void bbuild_kernel(const int2* __restrict__ ebuf, const int* __restrict__ bucketBase,
                   int shift, int N, int E, int* __restrict__ rowptr,
                   float* __restrict__ dinv, int* __restrict__ csr_src) {
    __shared__ int cnt[1024];
    __shared__ int exc[1024];
    __shared__ int bs[256];
    int b = blockIdx.x;
    int nodeBase = b << shift;
    int width = 1 << shift;
    int nn = N - nodeBase; if (nn > width) nn = width;
    int beg = bucketBase[b], end = bucketBase[b + 1];
    for (int i = threadIdx.x; i < width; i += 256) cnt[i] = 0;
    __syncthreads();
    for (int e = beg + threadIdx.x; e < end; e += 256)
        atomicAdd(&cnt[ebuf[e].y - nodeBase], 1);
    __syncthreads();
    // exclusive scan of cnt[0..width)
    int per = width / 256;          // 2 at shift=9
    int s = 0;
    int base4 = threadIdx.x * per;
    for (int i = 0; i < per; i++) s += cnt[base4 + i];
    bs[threadIdx.x] = s;
    __syncthreads();
    for (int off = 1; off < 256; off <<= 1) {
        int t = ((int)threadIdx.x >= off) ? bs[threadIdx.x - off] : 0;
        __syncthreads();
        bs[threadIdx.x] += t;
        __syncthreads();
    }
    int run = bs[threadIdx.x] - s;
    for (int i = 0; i < per; i++) { exc[base4 + i] = run; run += cnt[base4 + i]; }
    __syncthreads();
    // rowptr + dinv (coalesced)
    for (int i = threadIdx.x; i < nn; i += 256) {
        int node = nodeBase + i;
        rowptr[node] = beg + exc[i];
        dinv[node] = rsqrtf((float)cnt[i] + 1.0f);
    }
    __syncthreads();
    for (int i = threadIdx.x; i < width; i += 256) cnt[i] = 0;
    __syncthreads();
    // csr fill within local window
    for (int e = beg + threadIdx.x; e < end; e += 256) {
        int2 v = ebuf[e];
        int l = v.y - nodeBase;
        int p = atomicAdd(&cnt[l], 1);
        csr_src[beg + exc[l] + p] = v.x;
    }
    if (b == 0 && threadIdx.x == 0) rowptr[N] = E;
}

// ---------------------------------------------------------------- weight -> MFMA B-fragment packs
// frag f = kstep*ntiles + ntile; slot s = f*64 + lane; element j (0..7):
//   W[kstep*32 + (lane>>4)*8 + j][ntile*16 + (lane&15)]  (fw-aware fp32/bf16 read)
__global__ __launch_bounds__(256, 4)
void repack_kernel(const void* __restrict__ W1, const void* __restrict__ W2,
                   const void* __restrict__ Wl, const int* __restrict__ flags,
                   bf16* __restrict__ Bp1, bf16* __restrict__ Bp2, bf16* __restrict__ Bp3) {
    bool fw = flags[1] != 0;
    const void* W; bf16* Bp; int ntiles, nc, nfrag;
    if (blockIdx.x == 0)      { W = W1; Bp = Bp1; ntiles = 4; nc = 64; nfrag = 16; }
    else if (blockIdx.x == 1) { W = W2; Bp = Bp2; ntiles = 2; nc = 32; nfrag = 4;  }
    else                      { W = Wl; Bp = Bp3; ntiles = 2; nc = 32; nfrag = 14; }
    for (int s = threadIdx.x; s < nfrag * 64; s += 256) {
        int f = s >> 6, lane = s & 63;
        int kstep = f / ntiles, ntile = f % ntiles;
        int n = ntile * 16 + (lane & 15);
        int kbase = kstep * 32 + (lane >> 4) * 8;
#pragma unroll
        for (int j = 0; j < 8; j++)
            Bp[s * 8 + j] = __float2bfloat16(ldf(W, (long long)(kbase + j) * nc + n, fw));
    }
}

// ---------------------------------------------------------------- GEMM1 (MFMA): x[N,128]@W1 -> h1g[N,64] f16 rows
// R6: cvt_x fused in.  Reads f32 x directly (converts in-register for the MFMA
// A-frags) and writes xb (bf16) as a side product for final_mfma.  Deletes the
// standalone cvt kernel (77MB traffic) for +26MB here: net -26MB, -1 launch.
// Epilogue scales row r by dinv[r], stores f16 rows (gather miss-volume win, R3).
__global__ __launch_bounds__(256, 3)
void gemm1_mfma_kernel(const void* __restrict__ x, const bf16* __restrict__ Bpack,
                       const float* __restrict__ dinv, const int* __restrict__ flags,
                       __half* __restrict__ h1g, short* __restrict__ xb, int N) {
    bool fx = flags[0] != 0;
    int lane = threadIdx.x & 63, wave = threadIdx.x >> 6;
    int m = lane & 15, quad = lane >> 4;
    int base = blockIdx.x * 128 + wave * 32;
    if (base >= N) return;
    const short8* bp = (const short8*)Bpack;
    short8 B[16];
#pragma unroll
    for (int i = 0; i < 16; i++) B[i] = bp[i * 64 + lane];
    if (base + 32 <= N) {
#pragma unroll
        for (int t = 0; t < 2; t++) {
            int r0 = base + t * 16;
            short8 A[4];
            if (fx) {
                const float* xr = &((const float*)x)[(long long)(r0 + m) * 128 + quad * 8];
#pragma unroll
                for (int k = 0; k < 4; k++) {
                    float4 fa = *(const float4*)(xr + k * 32);
                    float4 fb = *(const float4*)(xr + k * 32 + 4);
                    short8 o;
                    o[0] = f2bs(fa.x); o[1] = f2bs(fa.y); o[2] = f2bs(fa.z); o[3] = f2bs(fa.w);
                    o[4] = f2bs(fb.x); o[5] = f2bs(fb.y); o[6] = f2bs(fb.z); o[7] = f2bs(fb.w);
                    A[k] = o;
                }
                short* xw = &xb[(long long)(r0 + m) * 128 + quad * 8];
#pragma unroll
                for (int k = 0; k < 4; k++) *(short8*)(xw + k * 32) = A[k];
            } else {
                const short* xr = &((const short*)x)[(long long)(r0 + m) * 128 + quad * 8];
#pragma unroll
                for (int k = 0; k < 4; k++) A[k] = *(const short8*)(xr + k * 32);
            }
            f32x4 acc[4];
#pragma unroll
            for (int nt = 0; nt < 4; nt++) acc[nt] = (f32x4){0.f, 0.f, 0.f, 0.f};
#pragma unroll
            for (int k = 0; k < 4; k++) {
#pragma unroll
                for (int nt = 0; nt < 4; nt++) acc[nt] = MFMA16(A[k], B[k * 4 + nt], acc[nt]);
            }
            // C/D: col = lane&15, row = quad*4 + r  [m89/m91]
            float dv[4];
#pragma unroll
            for (int r = 0; r < 4; r++) dv[r] = dinv[r0 + quad * 4 + r];
            __half* o = &h1g[(long long)(r0 + quad * 4) * 64 + m];
#pragma unroll
            for (int nt = 0; nt < 4; nt++) {
#pragma unroll
                for (int r = 0; r < 4; r++) o[(long long)r * 64 + nt * 16] = __float2half(acc[nt][r] * dv[r]);
            }
        }
    } else {
#pragma unroll
        for (int t = 0; t < 2; t++) {
            int r0 = base + t * 16;
            int row = r0 + m;
            short8 A[4];
#pragma unroll
            for (int k = 0; k < 4; k++) A[k] = (short8){0,0,0,0,0,0,0,0};
            if (row < N) {
                if (fx) {
                    const float* xr = &((const float*)x)[(long long)row * 128 + quad * 8];
#pragma unroll
                    for (int k = 0; k < 4; k++) {
                        float4 fa = *(const float4*)(xr + k * 32);
                        float4 fb = *(const float4*)(xr + k * 32 + 4);
                        short8 o;
                        o[0] = f2bs(fa.x); o[1] = f2bs(fa.y); o[2] = f2bs(fa.z); o[3] = f2bs(fa.w);
                        o[4] = f2bs(fb.x); o[5] = f2bs(fb.y); o[6] = f2bs(fb.z); o[7] = f2bs(fb.w);
                        A[k] = o;
                    }
                    short* xw = &xb[(long long)row * 128 + quad * 8];
#pragma unroll
                    for (int k = 0; k < 4; k++) *(short8*)(xw + k * 32) = A[k];
                } else {
                    const short* xr = &((const short*)x)[(long long)row * 128 + quad * 8];
#pragma unroll
                    for (int k = 0; k < 4; k++) A[k] = *(const short8*)(xr + k * 32);
                }
            }
            f32x4 acc[4];
#pragma unroll
            for (int nt = 0; nt < 4; nt++) acc[nt] = (f32x4){0.f, 0.f, 0.f, 0.f};
#pragma unroll
            for (int k = 0; k < 4; k++) {
#pragma unroll
                for (int nt = 0; nt < 4; nt++) acc[nt] = MFMA16(A[k], B[k * 4 + nt], acc[nt]);
            }
#pragma unroll
            for (int r = 0; r < 4; r++) {
                int orow = r0 + quad * 4 + r;
                if (orow < N) {
                    float dv = dinv[orow];
                    __half* o = &h1g[(long long)orow * 64 + m];
#pragma unroll
                    for (int nt = 0; nt < 4; nt++) o[nt * 16] = __float2half(acc[nt][r] * dv);
                }
            }
        }
    }
}

// ---------------------------------------------------------------- gather layer 1: one wave per NODE PAIR, combined edge stream
// R6: consecutive nodes' edges are CONTIGUOUS in CSR -> process pair (n0,n1) as
// ONE edge stream [beg,end) with mid=rowptr[n0+1] routing.  Accumulate
// all += v and n0 += v*(i<mid); n1 = all - n0 after the reduce.  Halves the
// per-node serial chain {rowptr s_load -> csr s_load -> row loads} (the R5
// limiter: ~3 dependent misses/node) with NO max-deg lockstep waste (R4 bug),
// no clamp in full batches, and half the tail waste.
__global__ __launch_bounds__(256, 8)
void gather1_kernel(const unsigned int* __restrict__ h1g, const float* __restrict__ dinv,
                    const int* __restrict__ rowptr, const int* __restrict__ csr_src,
                    const void* __restrict__ bptr, const int* __restrict__ flags,
                    unsigned int* __restrict__ h1b, int N) {
    bool fw = flags[1] != 0;
    int lane = threadIdx.x & 63;
    int c = lane & 31, hf = lane >> 5;
    int wv = __builtin_amdgcn_readfirstlane(threadIdx.x >> 6);
    int n0 = (blockIdx.x * 4 + wv) * 2;
    if (n0 >= N) return;
    bool has1 = (n0 + 1 < N);
    int beg = rowptr[n0];
    int mid = rowptr[n0 + 1];
    int end = has1 ? rowptr[n0 + 2] : mid;
    const unsigned int* hL = h1g + c;
    float aA0 = 0.f, aA1 = 0.f;   // sum over [beg,end)
    float aN0 = 0.f, aN1 = 0.f;   // sum over [beg,mid)  (node n0)
    int p = beg;
    // 32-edge unmasked batches (16 row-loads in flight)
    for (; p + 32 <= end; p += 32) {
        unsigned int v[16]; float r[16];
#pragma unroll
        for (int u = 0; u < 16; u++) {
            int s0 = csr_src[p + 2 * u];       // uniform, consecutive -> merged s_load
            int s1 = csr_src[p + 2 * u + 1];
            int s = hf ? s1 : s0;
            r[u] = ((p + 2 * u + hf) < mid) ? 1.f : 0.f;
            v[u] = hL[(long long)s * 32];
        }
#pragma unroll
        for (int u = 0; u < 16; u++) {
            float2 f = __half22float2(*(const __half2*)&v[u]);
            aA0 += f.x; aA1 += f.y;
            aN0 = fmaf(f.x, r[u], aN0);
            aN1 = fmaf(f.y, r[u], aN1);
        }
    }
    // 16-edge unmasked batch
    for (; p + 16 <= end; p += 16) {
        unsigned int v[8]; float r[8];
#pragma unroll
        for (int u = 0; u < 8; u++) {
            int s0 = csr_src[p + 2 * u];
            int s1 = csr_src[p + 2 * u + 1];
            int s = hf ? s1 : s0;
            r[u] = ((p + 2 * u + hf) < mid) ? 1.f : 0.f;
            v[u] = hL[(long long)s * 32];
        }
#pragma unroll
        for (int u = 0; u < 8; u++) {
            float2 f = __half22float2(*(const __half2*)&v[u]);
            aA0 += f.x; aA1 += f.y;
            aN0 = fmaf(f.x, r[u], aN0);
            aN1 = fmaf(f.y, r[u], aN1);
        }
    }
    // masked tail (<16 edges)
    if (p < end) {
        unsigned int v[8]; float mk[8], r[8];
#pragma unroll
        for (int u = 0; u < 8; u++) {
            int i0 = p + 2 * u, i1 = i0 + 1;
            int s0 = csr_src[(i0 < end) ? i0 : beg];
            int s1 = csr_src[(i1 < end) ? i1 : beg];
            int s = hf ? s1 : s0;
            int i = p + 2 * u + hf;
            mk[u] = (i < end) ? 1.f : 0.f;
            r[u]  = (i < mid) ? 1.f : 0.f;
            v[u] = hL[(long long)s * 32];
        }
#pragma unroll
        for (int u = 0; u < 8; u++) {
            float2 f = __half22float2(*(const __half2*)&v[u]);
            aA0 = fmaf(f.x, mk[u], aA0);
            aA1 = fmaf(f.y, mk[u], aA1);
            aN0 = fmaf(f.x, r[u], aN0);
            aN1 = fmaf(f.y, r[u], aN1);
        }
    }
    aA0 += __shfl_xor(aA0, 32); aA1 += __shfl_xor(aA1, 32);
    aN0 += __shfl_xor(aN0, 32); aN1 += __shfl_xor(aN1, 32);
    // half 0 stores n0 (aN), half 1 stores n1 (aA - aN): contiguous 256B wave store
    int node = n0 + hf;
    if (node < N) {
        float a0 = hf ? (aA0 - aN0) : aN0;
        float a1 = hf ? (aA1 - aN1) : aN1;
        unsigned int gsv = h1g[(long long)node * 32 + c];
        float2 gs = __half22float2(*(const __half2*)&gsv);
        float dvd = dinv[node];
        float o0 = dvd * (a0 + gs.x) + ldf(bptr, 2 * c, fw);
        float o1 = dvd * (a1 + gs.y) + ldf(bptr, 2 * c + 1, fw);
        h1b[(long long)node * 32 + c] = pack_bf16x2(fmaxf(o0, 0.f), fmaxf(o1, 0.f));
    }
}

// ---------------------------------------------------------------- GEMM2 (MFMA): h1b[N,64]@W2 -> h2g[N,32] f16 rows (dinv-scaled)
__global__ __launch_bounds__(256, 4)
void gemm2_mfma_kernel(const short* __restrict__ h1b, const bf16* __restrict__ Bpack,
                       const float* __restrict__ dinv, __half* __restrict__ h2g, int N) {
    int lane = threadIdx.x & 63, wave = threadIdx.x >> 6;
    int m = lane & 15, quad = lane >> 4;
    int r0 = blockIdx.x * 64 + wave * 16;
    if (r0 >= N) return;
    const short8* bp = (const short8*)Bpack;
    short8 B[4];
#pragma unroll
    for (int i = 0; i < 4; i++) B[i] = bp[i * 64 + lane];
    f32x4 acc0 = {0.f,0.f,0.f,0.f}, acc1 = {0.f,0.f,0.f,0.f};
    if (r0 + 16 <= N) {
        const short* xr = &h1b[(long long)(r0 + m) * 64 + quad * 8];
#pragma unroll
        for (int k = 0; k < 2; k++) {
            short8 A = *(const short8*)(xr + k * 32);
            acc0 = MFMA16(A, B[k * 2 + 0], acc0);
            acc1 = MFMA16(A, B[k * 2 + 1], acc1);
        }
        float dv[4];
#pragma unroll
        for (int r = 0; r < 4; r++) dv[r] = dinv[r0 + quad * 4 + r];
        __half* o = &h2g[(long long)(r0 + quad * 4) * 32 + m];
#pragma unroll
        for (int r = 0; r < 4; r++) {
            o[(long long)r * 32]      = __float2half(acc0[r] * dv[r]);
            o[(long long)r * 32 + 16] = __float2half(acc1[r] * dv[r]);
        }
    } else {
        int row = r0 + m;
#pragma unroll
        for (int k = 0; k < 2; k++) {
            short8 A = {0,0,0,0,0,0,0,0};
            if (row < N) A = *(const short8*)&h1b[(long long)row * 64 + k * 32 + quad * 8];
            acc0 = MFMA16(A, B[k * 2 + 0], acc0);
            acc1 = MFMA16(A, B[k * 2 + 1], acc1);
        }
#pragma unroll
        for (int r = 0; r < 4; r++) {
            int orow = r0 + quad * 4 + r;
            if (orow < N) {
                float dv = dinv[orow];
                h2g[(long long)orow * 32 + m]      = __float2half(acc0[r] * dv);
                h2g[(long long)orow * 32 + 16 + m] = __float2half(acc1[r] * dv);
            }
        }
    }
}

// ---------------------------------------------------------------- gather layer 2: node-pair combined stream (64B f16x2 rows)
// Same R6 routing trick: 16-lane group per edge, 4 edges per u-step over the
// pair's combined CSR range; all/n0 accumulators; sub 0/1 store n0/n1.
__global__ __launch_bounds__(256, 8)
void gather2_kernel(const unsigned int* __restrict__ h2g, const float* __restrict__ dinv,
                    const int* __restrict__ rowptr, const int* __restrict__ csr_src,
                    const void* __restrict__ bptr, const int* __restrict__ flags,
                    unsigned int* __restrict__ h2b, int N) {
    bool fw = flags[1] != 0;
    int lane = threadIdx.x & 63;
    int c = lane & 15, sub = lane >> 4;
    int wv = __builtin_amdgcn_readfirstlane(threadIdx.x >> 6);
    int n0 = (blockIdx.x * 4 + wv) * 2;
    if (n0 >= N) return;
    bool has1 = (n0 + 1 < N);
    int beg = rowptr[n0];
    int mid = rowptr[n0 + 1];
    int end = has1 ? rowptr[n0 + 2] : mid;
    const unsigned int* hL = h2g + c;
    float aA0 = 0.f, aA1 = 0.f, aN0 = 0.f, aN1 = 0.f;
    int p = beg;
    // 32-edge unmasked batches (8 loads in flight)
    for (; p + 32 <= end; p += 32) {
        unsigned int v[8]; float r[8];
#pragma unroll
        for (int u = 0; u < 8; u++) {
            int i0 = p + 4 * u;
            int sa0 = csr_src[i0], sa1 = csr_src[i0 + 1];
            int sa2 = csr_src[i0 + 2], sa3 = csr_src[i0 + 3];
            int sA = (sub & 1) ? sa1 : sa0;
            int sB = (sub & 1) ? sa3 : sa2;
            int s  = (sub & 2) ? sB : sA;
            r[u] = ((i0 + sub) < mid) ? 1.f : 0.f;
            v[u] = hL[(long long)s * 16];
        }
#pragma unroll
        for (int u = 0; u < 8; u++) {
            float2 f = __half22float2(*(const __half2*)&v[u]);
            aA0 += f.x; aA1 += f.y;
            aN0 = fmaf(f.x, r[u], aN0);
            aN1 = fmaf(f.y, r[u], aN1);
        }
    }
    // 16-edge unmasked batch
    for (; p + 16 <= end; p += 16) {
        unsigned int v[4]; float r[4];
#pragma unroll
        for (int u = 0; u < 4; u++) {
            int i0 = p + 4 * u;
            int sa0 = csr_src[i0], sa1 = csr_src[i0 + 1];
            int sa2 = csr_src[i0 + 2], sa3 = csr_src[i0 + 3];
            int sA = (sub & 1) ? sa1 : sa0;
            int sB = (sub & 1) ? sa3 : sa2;
            int s  = (sub & 2) ? sB : sA;
            r[u] = ((i0 + sub) < mid) ? 1.f : 0.f;
            v[u] = hL[(long long)s * 16];
        }
#pragma unroll
        for (int u = 0; u < 4; u++) {
            float2 f = __half22float2(*(const __half2*)&v[u]);
            aA0 += f.x; aA1 += f.y;
            aN0 = fmaf(f.x, r[u], aN0);
            aN1 = fmaf(f.y, r[u], aN1);
        }
    }
    // masked tail (<16 edges)
    if (p < end) {
        unsigned int v[4]; float mk[4], r[4];
#pragma unroll
        for (int u = 0; u < 4; u++) {
            int i0 = p + 4 * u;
            int sa0 = csr_src[(i0     < end) ? i0     : beg];
            int sa1 = csr_src[(i0 + 1 < end) ? i0 + 1 : beg];
            int sa2 = csr_src[(i0 + 2 < end) ? i0 + 2 : beg];
            int sa3 = csr_src[(i0 + 3 < end) ? i0 + 3 : beg];
            int sA = (sub & 1) ? sa1 : sa0;
            int sB = (sub & 1) ? sa3 : sa2;
            int s  = (sub & 2) ? sB : sA;
            int i = i0 + sub;
            mk[u] = (i < end) ? 1.f : 0.f;
            r[u]  = (i < mid) ? 1.f : 0.f;
            v[u] = hL[(long long)s * 16];
        }
#pragma unroll
        for (int u = 0; u < 4; u++) {
            float2 f = __half22float2(*(const __half2*)&v[u]);
            aA0 = fmaf(f.x, mk[u], aA0);
            aA1 = fmaf(f.y, mk[u], aA1);
            aN0 = fmaf(f.x, r[u], aN0);
            aN1 = fmaf(f.y, r[u], aN1);
        }
    }
    aA0 += __shfl_xor(aA0, 16); aA1 += __shfl_xor(aA1, 16);
    aN0 += __shfl_xor(aN0, 16); aN1 += __shfl_xor(aN1, 16);
    aA0 += __shfl_xor(aA0, 32); aA1 += __shfl_xor(aA1, 32);
    aN0 += __shfl_xor(aN0, 32); aN1 += __shfl_xor(aN1, 32);
    // sub 0 stores n0 (aN), sub 1 stores n1 (aA - aN): contiguous 128B store
    if (sub < 2) {
        int node = n0 + sub;
        if (node < N) {
            float a0 = sub ? (aA0 - aN0) : aN0;
            float a1 = sub ? (aA1 - aN1) : aN1;
            unsigned int gsv = h2g[(long long)node * 16 + c];
            float2 gs = __half22float2(*(const __half2*)&gsv);
            float dvd = dinv[node];
            float o0 = dvd * (a0 + gs.x) + ldf(bptr, 2 * c, fw);
            float o1 = dvd * (a1 + gs.y) + ldf(bptr, 2 * c + 1, fw);
            h2b[(long long)node * 16 + c] = pack_bf16x2(o0, o1);
        }
    }
}

// ---------------------------------------------------------------- final (MFMA): [x|h1b|h2b]@Wl + bl -> log_softmax
// R6: selects x (bf16 input) vs xb (gemm1-written bf16 copy of f32 input) via flags.
__global__ __launch_bounds__(256, 2)
void final_mfma_kernel(const void* __restrict__ x, const short* __restrict__ xb,
                       const short* __restrict__ h1b,
                       const short* __restrict__ h2b, const bf16* __restrict__ Bpack,
                       const void* __restrict__ bl, const int* __restrict__ flags,
                       void* __restrict__ out, int N) {
    bool fw = flags[1] != 0, fx = flags[0] != 0;
    const short* xs = fx ? xb : (const short*)x;
    int lane = threadIdx.x & 63, wave = threadIdx.x >> 6;
    int m = lane & 15, quad = lane >> 4;
    int r0 = blockIdx.x * 64 + wave * 16;
    if (r0 >= N) return;
    const short8* bp = (const short8*)Bpack;
    short8 B[14];
#pragma unroll
    for (int i = 0; i < 14; i++) B[i] = bp[i * 64 + lane];
    f32x4 acc0 = {0.f,0.f,0.f,0.f}, acc1 = {0.f,0.f,0.f,0.f};
    bool full = (r0 + 16 <= N);
    int row = r0 + m;
    bool rowok = full || (row < N);
#pragma unroll
    for (int s = 0; s < 7; s++) {
        short8 A = {0,0,0,0,0,0,0,0};
        if (rowok) {
            const short* p;
            if (s < 4)      p = &xs [(long long)row * 128 + s * 32 + quad * 8];
            else if (s < 6) p = &h1b[(long long)row * 64 + (s - 4) * 32 + quad * 8];
            else            p = &h2b[(long long)row * 32 + quad * 8];
            A = *(const short8*)p;
        }
        acc0 = MFMA16(A, B[s * 2 + 0], acc0);
        acc1 = MFMA16(A, B[s * 2 + 1], acc1);
    }
    float bl0 = ldf(bl, m, fw), bl1 = ldf(bl, m + 16, fw);
#pragma unroll
    for (int r = 0; r < 4; r++) {
        float v0 = acc0[r] + bl0, v1 = acc1[r] + bl1;
        float mx = fmaxf(v0, v1);
#pragma unroll
        for (int o = 8; o > 0; o >>= 1) mx = fmaxf(mx, __shfl_xor(mx, o));
        float sm = __expf(v0 - mx) + __expf(v1 - mx);
#pragma unroll
        for (int o = 8; o > 0; o >>= 1) sm += __shfl_xor(sm, o);
        float lse = mx + __logf(sm);
        int orow = r0 + quad * 4 + r;
        if (orow < N) {
            if (fx) {
                ((float*)out)[(long long)orow * 32 + m]      = v0 - lse;
                ((float*)out)[(long long)orow * 32 + 16 + m] = v1 - lse;
            } else {
                ((bf16*)out)[(long long)orow * 32 + m]      = __float2bfloat16(v0 - lse);
                ((bf16*)out)[(long long)orow * 32 + 16 + m] = __float2bfloat16(v1 - lse);
            }
        }
    }
}

extern "C" void kernel_launch(void* const* d_in, const int* in_sizes, int n_in,
                              void* d_out, int out_size, void* d_ws, size_t ws_size,
                              hipStream_t stream) {
    const void* x  = d_in[0];
    const int*  ei = (const int*)d_in[1];
    const void* W1 = d_in[2];
    const void* b1 = d_in[3];
    const void* W2 = d_in[4];
    const void* b2 = d_in[5];
    const void* Wl = d_in[6];
    const void* bl = d_in[7];

    int N = in_sizes[0] / 128;
    int E = in_sizes[1] / 2;

    int shift = 9;
    while (((N + (1 << shift) - 1) >> shift) > 256 && shift < 10) shift++;
    int NB = (N + (1 << shift) - 1) >> shift;   // 196 at N=100k

    // ws layout (4B units):
    // [flags 16 | bucketCount 256 | bucketBase 272 | bcursor 256 | dinv N | rowptr N+16 |
    //  Bp1 4096 | Bp2 1024 | Bp3 3584 | csr_src E | xb N*64 |
    //  A N*64 (ebuf int2 E<=N*32; then h1g f16 N*32; later h2g f16 N*16 + h2b N*16) | h1b N*32]
    int* ip      = (int*)d_ws;
    int* flags   = ip;
    int* bucketCount = ip + 16;
    int* bucketBase  = bucketCount + 256;
    int* bcursor     = bucketBase + 272;
    float* dinv  = (float*)(bcursor + 256);
    int* rowptr  = (int*)(dinv + N);
    bf16* Bp1    = (bf16*)(rowptr + N + 16);
    bf16* Bp2    = (bf16*)((int*)Bp1 + 4096);
    bf16* Bp3    = (bf16*)((int*)Bp2 + 1024);
    int* csr_src = (int*)Bp3 + 3584;
    short* xb    = (short*)(csr_src + E);                 // N*64 ints
    int*   Ai    = (int*)xb + (size_t)N * 64;             // region A: N*64 ints
    int2*  ebuf  = (int2*)Ai;                             // E*2 ints (dead before gemm1)
    __half* h1g  = (__half*)Ai;                           // N*64 halves = N*32 ints
    __half* h2g  = (__half*)Ai;                           // alias (h1g dead after gather1), N*16 ints
    unsigned int* h2b = (unsigned int*)(Ai + (size_t)N * 48);  // N*16 uints
    unsigned int* h1b = (unsigned int*)(Ai + (size_t)N * 64);  // N*32 uints

    // zero flags + bucketCount
    hipMemsetAsync(ip, 0, (16 + 256) * sizeof(int), stream);

    sniff_kernel<<<3, 256, 0, stream>>>(x, W1, ei, E, flags);

    int nchunk = (E + 4095) / 4096;
    bhist_kernel<<<nchunk, 256, 0, stream>>>(ei, E, flags, shift, NB, bucketCount);
    bscan_kernel<<<1, 256, 0, stream>>>(bucketCount, NB, bucketBase, bcursor, E);
    bpart_kernel<<<nchunk, 256, 0, stream>>>(ei, E, flags, shift, NB, bcursor, ebuf);
    bbuild_kernel<<<NB, 256, 0, stream>>>(ebuf, bucketBase, shift, N, E, rowptr, dinv, csr_src);

    repack_kernel<<<3, 256, 0, stream>>>(W1, W2, Wl, flags, Bp1, Bp2, Bp3);

    gemm1_mfma_kernel<<<(N + 127) / 128, 256, 0, stream>>>(x, Bp1, dinv, flags, h1g, xb, N);
    gather1_kernel<<<(N + 7) / 8, 256, 0, stream>>>((const unsigned int*)h1g, dinv, rowptr, csr_src,
                                                    b1, flags, h1b, N);
    gemm2_mfma_kernel<<<(N + 63) / 64, 256, 0, stream>>>((const short*)h1b, Bp2, dinv, h2g, N);
    gather2_kernel<<<(N + 7) / 8, 256, 0, stream>>>((const unsigned int*)h2g, dinv, rowptr, csr_src,
                                                    b2, flags, h2b, N);
    final_mfma_kernel<<<(N + 63) / 64, 256, 0, stream>>>(x, (const short*)xb, (const short*)h1b,
                                                         (const short*)h2b, Bp3, bl, flags, d_out, N);
}

// Round 8
// 285.099 us; speedup vs baseline: 1.1578x; 1.0283x over previous
//
#include <hip/hip_runtime.h>
#include <hip/hip_bf16.h>
#include <hip/hip_fp16.h>

typedef __hip_bfloat16 bf16;
typedef __attribute__((ext_vector_type(8))) short short8;   // 8 bf16 (4 VGPRs)
typedef __attribute__((ext_vector_type(4))) float f32x4;    // MFMA accumulator

#define MFMA16(a, b, c) __builtin_amdgcn_mfma_f32_16x16x32_bf16((a), (b), (c), 0, 0, 0)

// dual-mode float load: f32 ? float buffer : bf16 buffer (same element index)
static __device__ __forceinline__ float ldf(const void* p, long long i, bool f32) {
    return f32 ? ((const float*)p)[i] : __bfloat162float(((const bf16*)p)[i]);
}

static __device__ __forceinline__ short f2bs(float v) {
    union { bf16 h; short s; } u; u.h = __float2bfloat16(v); return u.s;
}

static __device__ __forceinline__ unsigned int pack_bf16x2(float a, float b) {
    return (unsigned int)(unsigned short)f2bs(a) | ((unsigned int)(unsigned short)f2bs(b) << 16);
}

static __device__ __forceinline__ int ld_src(const int* ei, int E, int e, bool i64) {
    return i64 ? ei[2 * e] : ei[e];
}
static __device__ __forceinline__ int ld_dst(const int* ei, int E, int e, bool i64) {
    return i64 ? ei[2 * (E + e)] : ei[E + e];
}

// ---------------------------------------------------------------- bucket CSR build
// shift=9: bucket b owns dst in [b*512, (b+1)*512). NB = ceil(N/512) <= 256.

// Pass A (R7 mega): blocks [0,nchunk) = histogram (block 0 also sniffs x->flags[0];
// each block self-detects int64 from the always-valid first 8KB of ei).
// Blocks nchunk..nchunk+1 = weight repack (W1->Bp1, Wl->Bp3) with local fw sniff;
// W1 block publishes flags[1].  Replaces the old sniff + repack launches.
__global__ __launch_bounds__(256, 4)
void bhist_kernel(const int* __restrict__ ei, int E,
                  const void* __restrict__ x, const void* __restrict__ W1,
                  const void* __restrict__ Wl,
                  int shift, int NB, int nchunk,
                  int* __restrict__ flags, int* __restrict__ bucketCount,
                  bf16* __restrict__ Bp1, bf16* __restrict__ Bp3) {
    __shared__ int h[256];
    __shared__ int sdet;
    int bid = blockIdx.x;
    if (bid >= nchunk) {
        // ---- repack role ----
        int which = bid - nchunk;                 // 0 -> W1, 1 -> Wl
        const void* W = which ? Wl : W1;
        bf16* Bp = which ? Bp3 : Bp1;
        int ntiles = which ? 2 : 4, nc = which ? 32 : 64, nfrag = which ? 14 : 16;
        if (threadIdx.x == 0) sdet = 0;
        __syncthreads();
        const unsigned short* u = (const unsigned short*)W;
        int bad = 0;
        for (int i = threadIdx.x; i < 4096; i += 256) {
            unsigned e = (u[i] >> 7) & 0xFF;
            if (e >= 0xA0) bad++;
        }
        if (bad) atomicAdd(&sdet, bad);
        __syncthreads();
        bool fw = sdet > 16;
        if (which == 0 && threadIdx.x == 0) flags[1] = fw ? 1 : 0;
        for (int s = threadIdx.x; s < nfrag * 64; s += 256) {
            int f = s >> 6, lane = s & 63;
            int kstep = f / ntiles, ntile = f % ntiles;
            int n = ntile * 16 + (lane & 15);
            int kbase = kstep * 32 + (lane >> 4) * 8;
#pragma unroll
            for (int j = 0; j < 8; j++)
                Bp[s * 8 + j] = __float2bfloat16(ldf(W, (long long)(kbase + j) * nc + n, fw));
        }
        return;
    }
    // ---- histogram role ----
    if (bid == 0) {
        // sniff x -> flags[0]
        if (threadIdx.x == 0) sdet = 0;
        __syncthreads();
        const unsigned short* u = (const unsigned short*)x;
        int bad = 0;
        for (int i = threadIdx.x; i < 4096; i += 256) {
            unsigned e = (u[i] >> 7) & 0xFF;
            if (e >= 0xA0) bad++;
        }
        if (bad) atomicAdd(&sdet, bad);
        __syncthreads();
        if (threadIdx.x == 0) flags[0] = (sdet > 16) ? 1 : 0;
        __syncthreads();
    }
    // block-local int64 detection (first 8KB of ei is valid in both layouts)
    if (threadIdx.x == 0) sdet = 0;
    for (int i = threadIdx.x; i < 256; i += 256) h[i] = 0;
    __syncthreads();
    {
        int nz = 0;
        for (int i = threadIdx.x; i < 1024; i += 256)
            if (2 * i + 1 < 2 * E && ei[2 * i + 1] != 0) nz++;
        if (nz) atomicAdd(&sdet, nz);
    }
    __syncthreads();
    bool i64 = (sdet == 0);
    int base = bid * 4096;
    for (int i = 0; i < 16; i++) {
        int e = base + i * 256 + threadIdx.x;
        if (e < E) atomicAdd(&h[ld_dst(ei, E, e, i64) >> shift], 1);
    }
    __syncthreads();
    for (int i = threadIdx.x; i < NB; i += 256)
        if (h[i]) atomicAdd(&bucketCount[i], h[i]);
}

// Pass C (R7): partition edges into bucket-contiguous ebuf.  Local int64
// detection + LOCAL scan of bucketCount (replaces bscan); bcursor is a
// zero-based per-bucket offset counter (memset-zeroed).  4096-edge LDS cache
// kills the second ei read (R4 win).
__global__ __launch_bounds__(256, 4)
void bpart_kernel(const int* __restrict__ ei, int E, int shift, int NB,
                  const int* __restrict__ bucketCount, int* __restrict__ bcursor,
                  int2* __restrict__ ebuf) {
    __shared__ int h[256];
    __shared__ int gofs[256];
    __shared__ int bs[256];
    __shared__ int2 se[4096];    // 32KB edge cache
    __shared__ int sdet;
    if (threadIdx.x == 0) sdet = 0;
    for (int i = threadIdx.x; i < 256; i += 256) h[i] = 0;
    __syncthreads();
    {
        int nz = 0;
        for (int i = threadIdx.x; i < 1024; i += 256)
            if (2 * i + 1 < 2 * E && ei[2 * i + 1] != 0) nz++;
        if (nz) atomicAdd(&sdet, nz);
    }
    __syncthreads();
    bool i64 = (sdet == 0);
    int base = blockIdx.x * 4096;
    // sweep 1: local histogram + LDS cache
    for (int i = 0; i < 16; i++) {
        int e = base + i * 256 + threadIdx.x;
        if (e < E) {
            int s = ld_src(ei, E, e, i64), d = ld_dst(ei, E, e, i64);
            se[i * 256 + threadIdx.x] = make_int2(s, d);
            atomicAdd(&h[d >> shift], 1);
        }
    }
    // local exclusive scan of bucketCount
    int v = ((int)threadIdx.x < NB) ? bucketCount[threadIdx.x] : 0;
    bs[threadIdx.x] = v;
    __syncthreads();
    for (int off = 1; off < 256; off <<= 1) {
        int t = ((int)threadIdx.x >= off) ? bs[threadIdx.x - off] : 0;
        __syncthreads();
        bs[threadIdx.x] += t;
        __syncthreads();
    }
    // claim contiguous global ranges (1 atomic per bucket per block)
    if ((int)threadIdx.x < NB) {
        int c = h[threadIdx.x];
        int b0 = bs[threadIdx.x] - v;            // exclusive bucket base
        gofs[threadIdx.x] = c ? (b0 + atomicAdd(&bcursor[threadIdx.x], c)) : 0;
    }
    __syncthreads();
    for (int i = threadIdx.x; i < 256; i += 256) h[i] = 0;
    __syncthreads();
    // sweep 2: write edges into claimed dense runs (from LDS)
    for (int i = 0; i < 16; i++) {
        int e = base + i * 256 + threadIdx.x;
        if (e < E) {
            int2 w = se[i * 256 + threadIdx.x];
            int b = w.y >> shift;
            int p = atomicAdd(&h[b], 1);
            ebuf[gofs[b] + p] = w;
        }
    }
}

// Pass D (R7): one block per bucket — beg/end from LOCAL bucketCount scan
// (bscan eliminated).  Local count, scan, rowptr+dinv write, csr fill.
__global__ __launch_bounds__(256, 2)
void bbuild_kernel(const int2* __restrict__ ebuf, const int* __restrict__ bucketCount,
                   int shift, int N, int E, int* __restrict__ rowptr,
                   float* __restrict__ dinv, int* __restrict__ csr_src) {
    __shared__ int cnt[1024];
    __shared__ int exc[1024];
    __shared__ int bs[256];
    int b = blockIdx.x;
    // local scan of bucketCount -> beg/end for this bucket
    int v = ((int)threadIdx.x < 256) ? bucketCount[threadIdx.x] : 0;
    bs[threadIdx.x] = v;
    __syncthreads();
    for (int off = 1; off < 256; off <<= 1) {
        int t = ((int)threadIdx.x >= off) ? bs[threadIdx.x - off] : 0;
        __syncthreads();
        bs[threadIdx.x] += t;
        __syncthreads();
    }
    int end = bs[b];
    int beg = end - bucketCount[b];
    __syncthreads();
    int nodeBase = b << shift;
    int width = 1 << shift;
    int nn = N - nodeBase; if (nn > width) nn = width;
    for (int i = threadIdx.x; i < width; i += 256) cnt[i] = 0;
    __syncthreads();
    for (int e = beg + threadIdx.x; e < end; e += 256)
        atomicAdd(&cnt[ebuf[e].y - nodeBase], 1);
    __syncthreads();
    // exclusive scan of cnt[0..width)
    int per = width / 256;          // 2 at shift=9
    int s = 0;
    int base4 = threadIdx.x * per;
    for (int i = 0; i < per; i++) s += cnt[base4 + i];
    bs[threadIdx.x] = s;
    __syncthreads();
    for (int off = 1; off < 256; off <<= 1) {
        int t = ((int)threadIdx.x >= off) ? bs[threadIdx.x - off] : 0;
        __syncthreads();
        bs[threadIdx.x] += t;
        __syncthreads();
    }
    int run = bs[threadIdx.x] - s;
    for (int i = 0; i < per; i++) { exc[base4 + i] = run; run += cnt[base4 + i]; }
    __syncthreads();
    // rowptr + dinv (coalesced)
    for (int i = threadIdx.x; i < nn; i += 256) {
        int node = nodeBase + i;
        rowptr[node] = beg + exc[i];
        dinv[node] = rsqrtf((float)cnt[i] + 1.0f);
    }
    __syncthreads();
    for (int i = threadIdx.x; i < width; i += 256) cnt[i] = 0;
    __syncthreads();
    // csr fill within local window
    for (int e = beg + threadIdx.x; e < end; e += 256) {
        int2 w = ebuf[e];
        int l = w.y - nodeBase;
        int p = atomicAdd(&cnt[l], 1);
        csr_src[beg + exc[l] + p] = w.x;
    }
    if (b == 0 && threadIdx.x == 0) rowptr[N] = E;
}

// ---------------------------------------------------------------- GEMM1 (MFMA): x[N,128]@W1 -> h1g[N,64] f16 rows
// cvt_x fused (R6): reads f32 x, converts in-register, writes xb side product.
// Epilogue scales row r by dinv[r], stores f16 rows (gather miss-volume win, R3).
__global__ __launch_bounds__(256, 3)
void gemm1_mfma_kernel(const void* __restrict__ x, const bf16* __restrict__ Bpack,
                       const float* __restrict__ dinv, const int* __restrict__ flags,
                       __half* __restrict__ h1g, short* __restrict__ xb, int N) {
    bool fx = flags[0] != 0;
    int lane = threadIdx.x & 63, wave = threadIdx.x >> 6;
    int m = lane & 15, quad = lane >> 4;
    int base = blockIdx.x * 128 + wave * 32;
    if (base >= N) return;
    const short8* bp = (const short8*)Bpack;
    short8 B[16];
#pragma unroll
    for (int i = 0; i < 16; i++) B[i] = bp[i * 64 + lane];
    if (base + 32 <= N) {
#pragma unroll
        for (int t = 0; t < 2; t++) {
            int r0 = base + t * 16;
            short8 A[4];
            if (fx) {
                const float* xr = &((const float*)x)[(long long)(r0 + m) * 128 + quad * 8];
#pragma unroll
                for (int k = 0; k < 4; k++) {
                    float4 fa = *(const float4*)(xr + k * 32);
                    float4 fb = *(const float4*)(xr + k * 32 + 4);
                    short8 o;
                    o[0] = f2bs(fa.x); o[1] = f2bs(fa.y); o[2] = f2bs(fa.z); o[3] = f2bs(fa.w);
                    o[4] = f2bs(fb.x); o[5] = f2bs(fb.y); o[6] = f2bs(fb.z); o[7] = f2bs(fb.w);
                    A[k] = o;
                }
                short* xw = &xb[(long long)(r0 + m) * 128 + quad * 8];
#pragma unroll
                for (int k = 0; k < 4; k++) *(short8*)(xw + k * 32) = A[k];
            } else {
                const short* xr = &((const short*)x)[(long long)(r0 + m) * 128 + quad * 8];
#pragma unroll
                for (int k = 0; k < 4; k++) A[k] = *(const short8*)(xr + k * 32);
            }
            f32x4 acc[4];
#pragma unroll
            for (int nt = 0; nt < 4; nt++) acc[nt] = (f32x4){0.f, 0.f, 0.f, 0.f};
#pragma unroll
            for (int k = 0; k < 4; k++) {
#pragma unroll
                for (int nt = 0; nt < 4; nt++) acc[nt] = MFMA16(A[k], B[k * 4 + nt], acc[nt]);
            }
            // C/D: col = lane&15, row = quad*4 + r  [m89/m91]
            float dv[4];
#pragma unroll
            for (int r = 0; r < 4; r++) dv[r] = dinv[r0 + quad * 4 + r];
            __half* o = &h1g[(long long)(r0 + quad * 4) * 64 + m];
#pragma unroll
            for (int nt = 0; nt < 4; nt++) {
#pragma unroll
                for (int r = 0; r < 4; r++) o[(long long)r * 64 + nt * 16] = __float2half(acc[nt][r] * dv[r]);
            }
        }
    } else {
#pragma unroll
        for (int t = 0; t < 2; t++) {
            int r0 = base + t * 16;
            int row = r0 + m;
            short8 A[4];
#pragma unroll
            for (int k = 0; k < 4; k++) A[k] = (short8){0,0,0,0,0,0,0,0};
            if (row < N) {
                if (fx) {
                    const float* xr = &((const float*)x)[(long long)row * 128 + quad * 8];
#pragma unroll
                    for (int k = 0; k < 4; k++) {
                        float4 fa = *(const float4*)(xr + k * 32);
                        float4 fb = *(const float4*)(xr + k * 32 + 4);
                        short8 o;
                        o[0] = f2bs(fa.x); o[1] = f2bs(fa.y); o[2] = f2bs(fa.z); o[3] = f2bs(fa.w);
                        o[4] = f2bs(fb.x); o[5] = f2bs(fb.y); o[6] = f2bs(fb.z); o[7] = f2bs(fb.w);
                        A[k] = o;
                    }
                    short* xw = &xb[(long long)row * 128 + quad * 8];
#pragma unroll
                    for (int k = 0; k < 4; k++) *(short8*)(xw + k * 32) = A[k];
                } else {
                    const short* xr = &((const short*)x)[(long long)row * 128 + quad * 8];
#pragma unroll
                    for (int k = 0; k < 4; k++) A[k] = *(const short8*)(xr + k * 32);
                }
            }
            f32x4 acc[4];
#pragma unroll
            for (int nt = 0; nt < 4; nt++) acc[nt] = (f32x4){0.f, 0.f, 0.f, 0.f};
#pragma unroll
            for (int k = 0; k < 4; k++) {
#pragma unroll
                for (int nt = 0; nt < 4; nt++) acc[nt] = MFMA16(A[k], B[k * 4 + nt], acc[nt]);
            }
#pragma unroll
            for (int r = 0; r < 4; r++) {
                int orow = r0 + quad * 4 + r;
                if (orow < N) {
                    float dv = dinv[orow];
                    __half* o = &h1g[(long long)orow * 64 + m];
#pragma unroll
                    for (int nt = 0; nt < 4; nt++) o[nt * 16] = __float2half(acc[nt][r] * dv);
                }
            }
        }
    }
}

// ---------------------------------------------------------------- gather layer 1 + fused GEMM2
// R7/R8: after the pair-combined gather reduce (R6), the wave holds each node's
// full h1 row -> stage 64 f32 in wave-local LDS, GEMV against LDS-resident W2
// (64x32), write h2g = dinv*(h1@W2) directly.  Eliminates the gemm2 kernel.
// R8 FIX: h2g must NOT alias h1g (R7 bug — concurrent write corrupted rows
// other blocks still gather-read).  h2g now lives at Ai+N*32 (disjoint).
__global__ __launch_bounds__(256, 8)
void gather1_kernel(const unsigned int* __restrict__ h1g, const float* __restrict__ dinv,
                    const int* __restrict__ rowptr, const int* __restrict__ csr_src,
                    const void* __restrict__ bptr, const void* __restrict__ W2,
                    const int* __restrict__ flags,
                    unsigned int* __restrict__ h1b, __half* __restrict__ h2g, int N) {
    __shared__ float w2s[64 * 32];      // 8KB
    __shared__ float h1s[4][2][64];     // 2KB, per-wave per-half staging
    bool fw = flags[1] != 0;
    // stage W2 before any divergence/returns
    for (int i = threadIdx.x; i < 2048; i += 256)
        w2s[i] = ldf(W2, i, fw);
    __syncthreads();
    int lane = threadIdx.x & 63;
    int c = lane & 31, hf = lane >> 5;
    int wv = __builtin_amdgcn_readfirstlane(threadIdx.x >> 6);
    int n0 = (blockIdx.x * 4 + wv) * 2;
    if (n0 >= N) return;
    bool has1 = (n0 + 1 < N);
    int beg = rowptr[n0];
    int mid = rowptr[n0 + 1];
    int end = has1 ? rowptr[n0 + 2] : mid;
    const unsigned int* hL = h1g + c;
    float aA0 = 0.f, aA1 = 0.f;   // sum over [beg,end)
    float aN0 = 0.f, aN1 = 0.f;   // sum over [beg,mid)  (node n0)
    int p = beg;
    // 32-edge unmasked batches (16 row-loads in flight)
    for (; p + 32 <= end; p += 32) {
        unsigned int v[16]; float r[16];
#pragma unroll
        for (int u = 0; u < 16; u++) {
            int s0 = csr_src[p + 2 * u];       // uniform, consecutive -> merged s_load
            int s1 = csr_src[p + 2 * u + 1];
            int s = hf ? s1 : s0;
            r[u] = ((p + 2 * u + hf) < mid) ? 1.f : 0.f;
            v[u] = hL[(long long)s * 32];
        }
#pragma unroll
        for (int u = 0; u < 16; u++) {
            float2 f = __half22float2(*(const __half2*)&v[u]);
            aA0 += f.x; aA1 += f.y;
            aN0 = fmaf(f.x, r[u], aN0);
            aN1 = fmaf(f.y, r[u], aN1);
        }
    }
    // 16-edge unmasked batch
    for (; p + 16 <= end; p += 16) {
        unsigned int v[8]; float r[8];
#pragma unroll
        for (int u = 0; u < 8; u++) {
            int s0 = csr_src[p + 2 * u];
            int s1 = csr_src[p + 2 * u + 1];
            int s = hf ? s1 : s0;
            r[u] = ((p + 2 * u + hf) < mid) ? 1.f : 0.f;
            v[u] = hL[(long long)s * 32];
        }
#pragma unroll
        for (int u = 0; u < 8; u++) {
            float2 f = __half22float2(*(const __half2*)&v[u]);
            aA0 += f.x; aA1 += f.y;
            aN0 = fmaf(f.x, r[u], aN0);
            aN1 = fmaf(f.y, r[u], aN1);
        }
    }
    // masked tail (<16 edges)
    if (p < end) {
        unsigned int v[8]; float mk[8], r[8];
#pragma unroll
        for (int u = 0; u < 8; u++) {
            int i0 = p + 2 * u, i1 = i0 + 1;
            int s0 = csr_src[(i0 < end) ? i0 : beg];
            int s1 = csr_src[(i1 < end) ? i1 : beg];
            int s = hf ? s1 : s0;
            int i = p + 2 * u + hf;
            mk[u] = (i < end) ? 1.f : 0.f;
            r[u]  = (i < mid) ? 1.f : 0.f;
            v[u] = hL[(long long)s * 32];
        }
#pragma unroll
        for (int u = 0; u < 8; u++) {
            float2 f = __half22float2(*(const __half2*)&v[u]);
            aA0 = fmaf(f.x, mk[u], aA0);
            aA1 = fmaf(f.y, mk[u], aA1);
            aN0 = fmaf(f.x, r[u], aN0);
            aN1 = fmaf(f.y, r[u], aN1);
        }
    }
    aA0 += __shfl_xor(aA0, 32); aA1 += __shfl_xor(aA1, 32);
    aN0 += __shfl_xor(aN0, 32); aN1 += __shfl_xor(aN1, 32);
    // epilogue: half hf owns node n0+hf
    int node = n0 + hf;
    int nodeC = (node < N) ? node : n0;
    float a0 = hf ? (aA0 - aN0) : aN0;
    float a1 = hf ? (aA1 - aN1) : aN1;
    unsigned int gsv = h1g[(long long)nodeC * 32 + c];
    float2 gs = __half22float2(*(const __half2*)&gsv);
    float dvd = dinv[nodeC];
    float o0 = fmaxf(dvd * (a0 + gs.x) + ldf(bptr, 2 * c, fw), 0.f);
    float o1 = fmaxf(dvd * (a1 + gs.y) + ldf(bptr, 2 * c + 1, fw), 0.f);
    if (node < N)
        h1b[(long long)node * 32 + c] = pack_bf16x2(o0, o1);
    // fused GEMM2: stage h1 row, GEMV vs W2, write h2g (dinv-scaled f16)
    h1s[wv][hf][2 * c]     = o0;
    h1s[wv][hf][2 * c + 1] = o1;
    __threadfence_block();             // LDS write->read visibility (same wave)
    const float* hrow = h1s[wv][hf];
    float acc = 0.f;
#pragma unroll 8
    for (int k = 0; k < 64; k++)
        acc = fmaf(hrow[k], w2s[k * 32 + c], acc);
    if (node < N)
        h2g[(long long)node * 32 + c] = __float2half(dvd * acc);
}

// ---------------------------------------------------------------- gather layer 2: node-pair combined stream (64B f16x2 rows)
__global__ __launch_bounds__(256, 8)
void gather2_kernel(const unsigned int* __restrict__ h2g, const float* __restrict__ dinv,
                    const int* __restrict__ rowptr, const int* __restrict__ csr_src,
                    const void* __restrict__ bptr, const int* __restrict__ flags,
                    unsigned int* __restrict__ h2b, int N) {
    bool fw = flags[1] != 0;
    int lane = threadIdx.x & 63;
    int c = lane & 15, sub = lane >> 4;
    int wv = __builtin_amdgcn_readfirstlane(threadIdx.x >> 6);
    int n0 = (blockIdx.x * 4 + wv) * 2;
    if (n0 >= N) return;
    bool has1 = (n0 + 1 < N);
    int beg = rowptr[n0];
    int mid = rowptr[n0 + 1];
    int end = has1 ? rowptr[n0 + 2] : mid;
    const unsigned int* hL = h2g + c;
    float aA0 = 0.f, aA1 = 0.f, aN0 = 0.f, aN1 = 0.f;
    int p = beg;
    // 32-edge unmasked batches (8 loads in flight)
    for (; p + 32 <= end; p += 32) {
        unsigned int v[8]; float r[8];
#pragma unroll
        for (int u = 0; u < 8; u++) {
            int i0 = p + 4 * u;
            int sa0 = csr_src[i0], sa1 = csr_src[i0 + 1];
            int sa2 = csr_src[i0 + 2], sa3 = csr_src[i0 + 3];
            int sA = (sub & 1) ? sa1 : sa0;
            int sB = (sub & 1) ? sa3 : sa2;
            int s  = (sub & 2) ? sB : sA;
            r[u] = ((i0 + sub) < mid) ? 1.f : 0.f;
            v[u] = hL[(long long)s * 16];
        }
#pragma unroll
        for (int u = 0; u < 8; u++) {
            float2 f = __half22float2(*(const __half2*)&v[u]);
            aA0 += f.x; aA1 += f.y;
            aN0 = fmaf(f.x, r[u], aN0);
            aN1 = fmaf(f.y, r[u], aN1);
        }
    }
    // 16-edge unmasked batch
    for (; p + 16 <= end; p += 16) {
        unsigned int v[4]; float r[4];
#pragma unroll
        for (int u = 0; u < 4; u++) {
            int i0 = p + 4 * u;
            int sa0 = csr_src[i0], sa1 = csr_src[i0 + 1];
            int sa2 = csr_src[i0 + 2], sa3 = csr_src[i0 + 3];
            int sA = (sub & 1) ? sa1 : sa0;
            int sB = (sub & 1) ? sa3 : sa2;
            int s  = (sub & 2) ? sB : sA;
            r[u] = ((i0 + sub) < mid) ? 1.f : 0.f;
            v[u] = hL[(long long)s * 16];
        }
#pragma unroll
        for (int u = 0; u < 4; u++) {
            float2 f = __half22float2(*(const __half2*)&v[u]);
            aA0 += f.x; aA1 += f.y;
            aN0 = fmaf(f.x, r[u], aN0);
            aN1 = fmaf(f.y, r[u], aN1);
        }
    }
    // masked tail (<16 edges)
    if (p < end) {
        unsigned int v[4]; float mk[4], r[4];
#pragma unroll
        for (int u = 0; u < 4; u++) {
            int i0 = p + 4 * u;
            int sa0 = csr_src[(i0     < end) ? i0     : beg];
            int sa1 = csr_src[(i0 + 1 < end) ? i0 + 1 : beg];
            int sa2 = csr_src[(i0 + 2 < end) ? i0 + 2 : beg];
            int sa3 = csr_src[(i0 + 3 < end) ? i0 + 3 : beg];
            int sA = (sub & 1) ? sa1 : sa0;
            int sB = (sub & 1) ? sa3 : sa2;
            int s  = (sub & 2) ? sB : sA;
            int i = i0 + sub;
            mk[u] = (i < end) ? 1.f : 0.f;
            r[u]  = (i < mid) ? 1.f : 0.f;
            v[u] = hL[(long long)s * 16];
        }
#pragma unroll
        for (int u = 0; u < 4; u++) {
            float2 f = __half22float2(*(const __half2*)&v[u]);
            aA0 = fmaf(f.x, mk[u], aA0);
            aA1 = fmaf(f.y, mk[u], aA1);
            aN0 = fmaf(f.x, r[u], aN0);
            aN1 = fmaf(f.y, r[u], aN1);
        }
    }
    aA0 += __shfl_xor(aA0, 16); aA1 += __shfl_xor(aA1, 16);
    aN0 += __shfl_xor(aN0, 16); aN1 += __shfl_xor(aN1, 16);
    aA0 += __shfl_xor(aA0, 32); aA1 += __shfl_xor(aA1, 32);
    aN0 += __shfl_xor(aN0, 32); aN1 += __shfl_xor(aN1, 32);
    // sub 0 stores n0 (aN), sub 1 stores n1 (aA - aN): contiguous 128B store
    if (sub < 2) {
        int node = n0 + sub;
        if (node < N) {
            float a0 = sub ? (aA0 - aN0) : aN0;
            float a1 = sub ? (aA1 - aN1) : aN1;
            unsigned int gsv = h2g[(long long)node * 16 + c];
            float2 gs = __half22float2(*(const __half2*)&gsv);
            float dvd = dinv[node];
            float o0 = dvd * (a0 + gs.x) + ldf(bptr, 2 * c, fw);
            float o1 = dvd * (a1 + gs.y) + ldf(bptr, 2 * c + 1, fw);
            h2b[(long long)node * 16 + c] = pack_bf16x2(o0, o1);
        }
    }
}

// ---------------------------------------------------------------- final (MFMA): [x|h1b|h2b]@Wl + bl -> log_softmax
__global__ __launch_bounds__(256, 2)
void final_mfma_kernel(const void* __restrict__ x, const short* __restrict__ xb,
                       const short* __restrict__ h1b,
                       const short* __restrict__ h2b, const bf16* __restrict__ Bpack,
                       const void* __restrict__ bl, const int* __restrict__ flags,
                       void* __restrict__ out, int N) {
    bool fw = flags[1] != 0, fx = flags[0] != 0;
    const short* xs = fx ? xb : (const short*)x;
    int lane = threadIdx.x & 63, wave = threadIdx.x >> 6;
    int m = lane & 15, quad = lane >> 4;
    int r0 = blockIdx.x * 64 + wave * 16;
    if (r0 >= N) return;
    const short8* bp = (const short8*)Bpack;
    short8 B[14];
#pragma unroll
    for (int i = 0; i < 14; i++) B[i] = bp[i * 64 + lane];
    f32x4 acc0 = {0.f,0.f,0.f,0.f}, acc1 = {0.f,0.f,0.f,0.f};
    bool full = (r0 + 16 <= N);
    int row = r0 + m;
    bool rowok = full || (row < N);
#pragma unroll
    for (int s = 0; s < 7; s++) {
        short8 A = {0,0,0,0,0,0,0,0};
        if (rowok) {
            const short* p;
            if (s < 4)      p = &xs [(long long)row * 128 + s * 32 + quad * 8];
            else if (s < 6) p = &h1b[(long long)row * 64 + (s - 4) * 32 + quad * 8];
            else            p = &h2b[(long long)row * 32 + quad * 8];
            A = *(const short8*)p;
        }
        acc0 = MFMA16(A, B[s * 2 + 0], acc0);
        acc1 = MFMA16(A, B[s * 2 + 1], acc1);
    }
    float bl0 = ldf(bl, m, fw), bl1 = ldf(bl, m + 16, fw);
#pragma unroll
    for (int r = 0; r < 4; r++) {
        float v0 = acc0[r] + bl0, v1 = acc1[r] + bl1;
        float mx = fmaxf(v0, v1);
#pragma unroll
        for (int o = 8; o > 0; o >>= 1) mx = fmaxf(mx, __shfl_xor(mx, o));
        float sm = __expf(v0 - mx) + __expf(v1 - mx);
#pragma unroll
        for (int o = 8; o > 0; o >>= 1) sm += __shfl_xor(sm, o);
        float lse = mx + __logf(sm);
        int orow = r0 + quad * 4 + r;
        if (orow < N) {
            if (fx) {
                ((float*)out)[(long long)orow * 32 + m]      = v0 - lse;
                ((float*)out)[(long long)orow * 32 + 16 + m] = v1 - lse;
            } else {
                ((bf16*)out)[(long long)orow * 32 + m]      = __float2bfloat16(v0 - lse);
                ((bf16*)out)[(long long)orow * 32 + 16 + m] = __float2bfloat16(v1 - lse);
            }
        }
    }
}

extern "C" void kernel_launch(void* const* d_in, const int* in_sizes, int n_in,
                              void* d_out, int out_size, void* d_ws, size_t ws_size,
                              hipStream_t stream) {
    const void* x  = d_in[0];
    const int*  ei = (const int*)d_in[1];
    const void* W1 = d_in[2];
    const void* b1 = d_in[3];
    const void* W2 = d_in[4];
    const void* b2 = d_in[5];
    const void* Wl = d_in[6];
    const void* bl = d_in[7];

    int N = in_sizes[0] / 128;
    int E = in_sizes[1] / 2;

    int shift = 9;
    while (((N + (1 << shift) - 1) >> shift) > 256 && shift < 10) shift++;
    int NB = (N + (1 << shift) - 1) >> shift;   // 196 at N=100k

    // ws layout (4B units):
    // [flags 16 | bucketCount 256 | bucketBase 272 (dead) | bcursor 256 | dinv N | rowptr N+16 |
    //  Bp1 4096 | Bp2 1024 (dead) | Bp3 3584 | csr_src E | xb N*64 |
    //  A N*64: h1g f16 [0,N*32) | h2g f16 [N*32,N*48) | h2b [N*48,N*64)   (ebuf int2 E*2<=N*64, dead before gemm1)
    //  | h1b N*32]
    int* ip      = (int*)d_ws;
    int* flags   = ip;
    int* bucketCount = ip + 16;
    int* bucketBase  = bucketCount + 256;   // dead, layout kept
    int* bcursor     = bucketBase + 272;
    float* dinv  = (float*)(bcursor + 256);
    int* rowptr  = (int*)(dinv + N);
    bf16* Bp1    = (bf16*)(rowptr + N + 16);
    bf16* Bp2    = (bf16*)((int*)Bp1 + 4096);  // dead
    bf16* Bp3    = (bf16*)((int*)Bp2 + 1024);
    int* csr_src = (int*)Bp3 + 3584;
    short* xb    = (short*)(csr_src + E);                 // N*64 ints
    int*   Ai    = (int*)xb + (size_t)N * 64;             // region A: N*64 ints
    int2*  ebuf  = (int2*)Ai;                             // E*2 ints (dead before gemm1)
    __half* h1g  = (__half*)Ai;                           // [0, N*32) ints
    __half* h2g  = (__half*)(Ai + (size_t)N * 32);        // [N*32, N*48) ints — R8 FIX: disjoint from h1g
    unsigned int* h2b = (unsigned int*)(Ai + (size_t)N * 48);  // [N*48, N*64) ints
    unsigned int* h1b = (unsigned int*)(Ai + (size_t)N * 64);  // N*32 uints

    // zero flags + bucketCount + bucketBase + bcursor (contiguous 800 ints)
    hipMemsetAsync(ip, 0, 800 * sizeof(int), stream);

    int nchunk = (E + 4095) / 4096;
    bhist_kernel<<<nchunk + 2, 256, 0, stream>>>(ei, E, x, W1, Wl, shift, NB, nchunk,
                                                 flags, bucketCount, Bp1, Bp3);
    bpart_kernel<<<nchunk, 256, 0, stream>>>(ei, E, shift, NB, bucketCount, bcursor, ebuf);
    bbuild_kernel<<<NB, 256, 0, stream>>>(ebuf, bucketCount, shift, N, E, rowptr, dinv, csr_src);

    gemm1_mfma_kernel<<<(N + 127) / 128, 256, 0, stream>>>(x, Bp1, dinv, flags, h1g, xb, N);
    gather1_kernel<<<(N + 7) / 8, 256, 0, stream>>>((const unsigned int*)h1g, dinv, rowptr, csr_src,
                                                    b1, W2, flags, h1b, h2g, N);
    gather2_kernel<<<(N + 7) / 8, 256, 0, stream>>>((const unsigned int*)h2g, dinv, rowptr, csr_src,
                                                    b2, flags, h2b, N);
    final_mfma_kernel<<<(N + 63) / 64, 256, 0, stream>>>(x, (const short*)xb, (const short*)h1b,
                                                         (const short*)h2b, Bp3, bl, flags, d_out, N);
}

// Round 9
// 279.169 us; speedup vs baseline: 1.1824x; 1.0212x over previous
//
#include <hip/hip_runtime.h>
#include <hip/hip_bf16.h>
#include <hip/hip_fp16.h>

typedef __hip_bfloat16 bf16;
typedef __attribute__((ext_vector_type(8))) short short8;   // 8 bf16 (4 VGPRs)
typedef __attribute__((ext_vector_type(4))) float f32x4;    // MFMA accumulator
typedef __attribute__((ext_vector_type(2))) float f32x2;
typedef _Float16 h16x2 __attribute__((ext_vector_type(2)));

#define MFMA16(a, b, c) __builtin_amdgcn_mfma_f32_16x16x32_bf16((a), (b), (c), 0, 0, 0)

// dual-mode float load: f32 ? float buffer : bf16 buffer (same element index)
static __device__ __forceinline__ float ldf(const void* p, long long i, bool f32) {
    return f32 ? ((const float*)p)[i] : __bfloat162float(((const bf16*)p)[i]);
}

static __device__ __forceinline__ short f2bs(float v) {
    union { bf16 h; short s; } u; u.h = __float2bfloat16(v); return u.s;
}

static __device__ __forceinline__ unsigned int pack_bf16x2(float a, float b) {
    return (unsigned int)(unsigned short)f2bs(a) | ((unsigned int)(unsigned short)f2bs(b) << 16);
}

static __device__ __forceinline__ unsigned int pack_h2(float a, float b) {
    __half2 hh = __floats2half2_rn(a, b);
    union { __half2 h; unsigned int u; } cv; cv.h = hh; return cv.u;
}

static __device__ __forceinline__ h16x2 as_h2(unsigned int u) {
    union { unsigned int u; h16x2 h; } cv; cv.u = u; return cv.h;
}

// fp8 e4m3 (OCP on gfx950) pack/unpack via HW cvt
static __device__ __forceinline__ unsigned char f32_to_fp8(float v) {
    int pk = __builtin_amdgcn_cvt_pk_fp8_f32(v, 0.f, 0, false);
    return (unsigned char)(pk & 0xFF);
}
static __device__ __forceinline__ f32x2 fp8x2_to_f32x2(unsigned short v) {
    return __builtin_amdgcn_cvt_pk_f32_fp8((int)v, false);
}

static __device__ __forceinline__ int ld_src(const int* ei, int E, int e, bool i64) {
    return i64 ? ei[2 * e] : ei[e];
}
static __device__ __forceinline__ int ld_dst(const int* ei, int E, int e, bool i64) {
    return i64 ? ei[2 * (E + e)] : ei[E + e];
}

// ---------------------------------------------------------------- bucket CSR build
// shift=9: bucket b owns dst in [b*512, (b+1)*512). NB = ceil(N/512) <= 256.

// Pass A (R7 mega): blocks [0,nchunk) = histogram (block 0 also sniffs x->flags[0];
// each block self-detects int64 from the always-valid first 8KB of ei).
// Blocks nchunk..nchunk+1 = weight repack (W1->Bp1, Wl->Bp3) with local fw sniff;
// W1 block publishes flags[1].
__global__ __launch_bounds__(256, 4)
void bhist_kernel(const int* __restrict__ ei, int E,
                  const void* __restrict__ x, const void* __restrict__ W1,
                  const void* __restrict__ Wl,
                  int shift, int NB, int nchunk,
                  int* __restrict__ flags, int* __restrict__ bucketCount,
                  bf16* __restrict__ Bp1, bf16* __restrict__ Bp3) {
    __shared__ int h[256];
    __shared__ int sdet;
    int bid = blockIdx.x;
    if (bid >= nchunk) {
        // ---- repack role ----
        int which = bid - nchunk;                 // 0 -> W1, 1 -> Wl
        const void* W = which ? Wl : W1;
        bf16* Bp = which ? Bp3 : Bp1;
        int ntiles = which ? 2 : 4, nc = which ? 32 : 64, nfrag = which ? 14 : 16;
        if (threadIdx.x == 0) sdet = 0;
        __syncthreads();
        const unsigned short* u = (const unsigned short*)W;
        int bad = 0;
        for (int i = threadIdx.x; i < 4096; i += 256) {
            unsigned e = (u[i] >> 7) & 0xFF;
            if (e >= 0xA0) bad++;
        }
        if (bad) atomicAdd(&sdet, bad);
        __syncthreads();
        bool fw = sdet > 16;
        if (which == 0 && threadIdx.x == 0) flags[1] = fw ? 1 : 0;
        for (int s = threadIdx.x; s < nfrag * 64; s += 256) {
            int f = s >> 6, lane = s & 63;
            int kstep = f / ntiles, ntile = f % ntiles;
            int n = ntile * 16 + (lane & 15);
            int kbase = kstep * 32 + (lane >> 4) * 8;
#pragma unroll
            for (int j = 0; j < 8; j++)
                Bp[s * 8 + j] = __float2bfloat16(ldf(W, (long long)(kbase + j) * nc + n, fw));
        }
        return;
    }
    // ---- histogram role ----
    if (bid == 0) {
        // sniff x -> flags[0]
        if (threadIdx.x == 0) sdet = 0;
        __syncthreads();
        const unsigned short* u = (const unsigned short*)x;
        int bad = 0;
        for (int i = threadIdx.x; i < 4096; i += 256) {
            unsigned e = (u[i] >> 7) & 0xFF;
            if (e >= 0xA0) bad++;
        }
        if (bad) atomicAdd(&sdet, bad);
        __syncthreads();
        if (threadIdx.x == 0) flags[0] = (sdet > 16) ? 1 : 0;
        __syncthreads();
    }
    // block-local int64 detection (first 8KB of ei is valid in both layouts)
    if (threadIdx.x == 0) sdet = 0;
    for (int i = threadIdx.x; i < 256; i += 256) h[i] = 0;
    __syncthreads();
    {
        int nz = 0;
        for (int i = threadIdx.x; i < 1024; i += 256)
            if (2 * i + 1 < 2 * E && ei[2 * i + 1] != 0) nz++;
        if (nz) atomicAdd(&sdet, nz);
    }
    __syncthreads();
    bool i64 = (sdet == 0);
    int base = bid * 4096;
    for (int i = 0; i < 16; i++) {
        int e = base + i * 256 + threadIdx.x;
        if (e < E) atomicAdd(&h[ld_dst(ei, E, e, i64) >> shift], 1);
    }
    __syncthreads();
    for (int i = threadIdx.x; i < NB; i += 256)
        if (h[i]) atomicAdd(&bucketCount[i], h[i]);
}

// Pass C (R7): partition edges into bucket-contiguous ebuf.  Local int64
// detection + LOCAL scan of bucketCount; bcursor is a zero-based per-bucket
// offset counter (memset-zeroed).  4096-edge LDS cache kills the second ei read.
__global__ __launch_bounds__(256, 4)
void bpart_kernel(const int* __restrict__ ei, int E, int shift, int NB,
                  const int* __restrict__ bucketCount, int* __restrict__ bcursor,
                  int2* __restrict__ ebuf) {
    __shared__ int h[256];
    __shared__ int gofs[256];
    __shared__ int bs[256];
    __shared__ int2 se[4096];    // 32KB edge cache
    __shared__ int sdet;
    if (threadIdx.x == 0) sdet = 0;
    for (int i = threadIdx.x; i < 256; i += 256) h[i] = 0;
    __syncthreads();
    {
        int nz = 0;
        for (int i = threadIdx.x; i < 1024; i += 256)
            if (2 * i + 1 < 2 * E && ei[2 * i + 1] != 0) nz++;
        if (nz) atomicAdd(&sdet, nz);
    }
    __syncthreads();
    bool i64 = (sdet == 0);
    int base = blockIdx.x * 4096;
    // sweep 1: local histogram + LDS cache
    for (int i = 0; i < 16; i++) {
        int e = base + i * 256 + threadIdx.x;
        if (e < E) {
            int s = ld_src(ei, E, e, i64), d = ld_dst(ei, E, e, i64);
            se[i * 256 + threadIdx.x] = make_int2(s, d);
            atomicAdd(&h[d >> shift], 1);
        }
    }
    // local exclusive scan of bucketCount
    int v = ((int)threadIdx.x < NB) ? bucketCount[threadIdx.x] : 0;
    bs[threadIdx.x] = v;
    __syncthreads();
    for (int off = 1; off < 256; off <<= 1) {
        int t = ((int)threadIdx.x >= off) ? bs[threadIdx.x - off] : 0;
        __syncthreads();
        bs[threadIdx.x] += t;
        __syncthreads();
    }
    // claim contiguous global ranges (1 atomic per bucket per block)
    if ((int)threadIdx.x < NB) {
        int c = h[threadIdx.x];
        int b0 = bs[threadIdx.x] - v;            // exclusive bucket base
        gofs[threadIdx.x] = c ? (b0 + atomicAdd(&bcursor[threadIdx.x], c)) : 0;
    }
    __syncthreads();
    for (int i = threadIdx.x; i < 256; i += 256) h[i] = 0;
    __syncthreads();
    // sweep 2: write edges into claimed dense runs (from LDS)
    for (int i = 0; i < 16; i++) {
        int e = base + i * 256 + threadIdx.x;
        if (e < E) {
            int2 w = se[i * 256 + threadIdx.x];
            int b = w.y >> shift;
            int p = atomicAdd(&h[b], 1);
            ebuf[gofs[b] + p] = w;
        }
    }
}

// Pass D (R7): one block per bucket — beg/end from LOCAL bucketCount scan.
__global__ __launch_bounds__(256, 2)
void bbuild_kernel(const int2* __restrict__ ebuf, const int* __restrict__ bucketCount,
                   int shift, int N, int E, int* __restrict__ rowptr,
                   float* __restrict__ dinv, int* __restrict__ csr_src) {
    __shared__ int cnt[1024];
    __shared__ int exc[1024];
    __shared__ int bs[256];
    int b = blockIdx.x;
    // local scan of bucketCount -> beg/end for this bucket
    int v = ((int)threadIdx.x < 256) ? bucketCount[threadIdx.x] : 0;
    bs[threadIdx.x] = v;
    __syncthreads();
    for (int off = 1; off < 256; off <<= 1) {
        int t = ((int)threadIdx.x >= off) ? bs[threadIdx.x - off] : 0;
        __syncthreads();
        bs[threadIdx.x] += t;
        __syncthreads();
    }
    int end = bs[b];
    int beg = end - bucketCount[b];
    __syncthreads();
    int nodeBase = b << shift;
    int width = 1 << shift;
    int nn = N - nodeBase; if (nn > width) nn = width;
    for (int i = threadIdx.x; i < width; i += 256) cnt[i] = 0;
    __syncthreads();
    for (int e = beg + threadIdx.x; e < end; e += 256)
        atomicAdd(&cnt[ebuf[e].y - nodeBase], 1);
    __syncthreads();
    // exclusive scan of cnt[0..width)
    int per = width / 256;          // 2 at shift=9
    int s = 0;
    int base4 = threadIdx.x * per;
    for (int i = 0; i < per; i++) s += cnt[base4 + i];
    bs[threadIdx.x] = s;
    __syncthreads();
    for (int off = 1; off < 256; off <<= 1) {
        int t = ((int)threadIdx.x >= off) ? bs[threadIdx.x - off] : 0;
        __syncthreads();
        bs[threadIdx.x] += t;
        __syncthreads();
    }
    int run = bs[threadIdx.x] - s;
    for (int i = 0; i < per; i++) { exc[base4 + i] = run; run += cnt[base4 + i]; }
    __syncthreads();
    // rowptr + dinv (coalesced)
    for (int i = threadIdx.x; i < nn; i += 256) {
        int node = nodeBase + i;
        rowptr[node] = beg + exc[i];
        dinv[node] = rsqrtf((float)cnt[i] + 1.0f);
    }
    __syncthreads();
    for (int i = threadIdx.x; i < width; i += 256) cnt[i] = 0;
    __syncthreads();
    // csr fill within local window
    for (int e = beg + threadIdx.x; e < end; e += 256) {
        int2 w = ebuf[e];
        int l = w.y - nodeBase;
        int p = atomicAdd(&cnt[l], 1);
        csr_src[beg + exc[l] + p] = w.x;
    }
    if (b == 0 && threadIdx.x == 0) rowptr[N] = E;
}

// ---------------------------------------------------------------- GEMM1 (MFMA): x[N,128]@W1 -> h1g[N,64] fp8 rows
// cvt_x fused (R6): reads f32 x, converts in-register, writes xb side product.
// R9: h1g stored as fp8 e4m3 (64B rows, ONE cache line) — halves the gather's
// random-fetch volume again (the 161MB @ ~3.4TB/s wall is volume-bound).
__global__ __launch_bounds__(256, 3)
void gemm1_mfma_kernel(const void* __restrict__ x, const bf16* __restrict__ Bpack,
                       const float* __restrict__ dinv, const int* __restrict__ flags,
                       unsigned char* __restrict__ h1g, short* __restrict__ xb, int N) {
    bool fx = flags[0] != 0;
    int lane = threadIdx.x & 63, wave = threadIdx.x >> 6;
    int m = lane & 15, quad = lane >> 4;
    int base = blockIdx.x * 128 + wave * 32;
    if (base >= N) return;
    const short8* bp = (const short8*)Bpack;
    short8 B[16];
#pragma unroll
    for (int i = 0; i < 16; i++) B[i] = bp[i * 64 + lane];
    if (base + 32 <= N) {
#pragma unroll
        for (int t = 0; t < 2; t++) {
            int r0 = base + t * 16;
            short8 A[4];
            if (fx) {
                const float* xr = &((const float*)x)[(long long)(r0 + m) * 128 + quad * 8];
#pragma unroll
                for (int k = 0; k < 4; k++) {
                    float4 fa = *(const float4*)(xr + k * 32);
                    float4 fb = *(const float4*)(xr + k * 32 + 4);
                    short8 o;
                    o[0] = f2bs(fa.x); o[1] = f2bs(fa.y); o[2] = f2bs(fa.z); o[3] = f2bs(fa.w);
                    o[4] = f2bs(fb.x); o[5] = f2bs(fb.y); o[6] = f2bs(fb.z); o[7] = f2bs(fb.w);
                    A[k] = o;
                }
                short* xw = &xb[(long long)(r0 + m) * 128 + quad * 8];
#pragma unroll
                for (int k = 0; k < 4; k++) *(short8*)(xw + k * 32) = A[k];
            } else {
                const short* xr = &((const short*)x)[(long long)(r0 + m) * 128 + quad * 8];
#pragma unroll
                for (int k = 0; k < 4; k++) A[k] = *(const short8*)(xr + k * 32);
            }
            f32x4 acc[4];
#pragma unroll
            for (int nt = 0; nt < 4; nt++) acc[nt] = (f32x4){0.f, 0.f, 0.f, 0.f};
#pragma unroll
            for (int k = 0; k < 4; k++) {
#pragma unroll
                for (int nt = 0; nt < 4; nt++) acc[nt] = MFMA16(A[k], B[k * 4 + nt], acc[nt]);
            }
            // C/D: col = lane&15, row = quad*4 + r  [m89/m91]
            float dv[4];
#pragma unroll
            for (int r = 0; r < 4; r++) dv[r] = dinv[r0 + quad * 4 + r];
            unsigned char* o = &h1g[(long long)(r0 + quad * 4) * 64 + m];
#pragma unroll
            for (int nt = 0; nt < 4; nt++) {
#pragma unroll
                for (int r = 0; r < 4; r++) o[(long long)r * 64 + nt * 16] = f32_to_fp8(acc[nt][r] * dv[r]);
            }
        }
    } else {
#pragma unroll
        for (int t = 0; t < 2; t++) {
            int r0 = base + t * 16;
            int row = r0 + m;
            short8 A[4];
#pragma unroll
            for (int k = 0; k < 4; k++) A[k] = (short8){0,0,0,0,0,0,0,0};
            if (row < N) {
                if (fx) {
                    const float* xr = &((const float*)x)[(long long)row * 128 + quad * 8];
#pragma unroll
                    for (int k = 0; k < 4; k++) {
                        float4 fa = *(const float4*)(xr + k * 32);
                        float4 fb = *(const float4*)(xr + k * 32 + 4);
                        short8 o;
                        o[0] = f2bs(fa.x); o[1] = f2bs(fa.y); o[2] = f2bs(fa.z); o[3] = f2bs(fa.w);
                        o[4] = f2bs(fb.x); o[5] = f2bs(fb.y); o[6] = f2bs(fb.z); o[7] = f2bs(fb.w);
                        A[k] = o;
                    }
                    short* xw = &xb[(long long)row * 128 + quad * 8];
#pragma unroll
                    for (int k = 0; k < 4; k++) *(short8*)(xw + k * 32) = A[k];
                } else {
                    const short* xr = &((const short*)x)[(long long)row * 128 + quad * 8];
#pragma unroll
                    for (int k = 0; k < 4; k++) A[k] = *(const short8*)(xr + k * 32);
                }
            }
            f32x4 acc[4];
#pragma unroll
            for (int nt = 0; nt < 4; nt++) acc[nt] = (f32x4){0.f, 0.f, 0.f, 0.f};
#pragma unroll
            for (int k = 0; k < 4; k++) {
#pragma unroll
                for (int nt = 0; nt < 4; nt++) acc[nt] = MFMA16(A[k], B[k * 4 + nt], acc[nt]);
            }
#pragma unroll
            for (int r = 0; r < 4; r++) {
                int orow = r0 + quad * 4 + r;
                if (orow < N) {
                    float dv = dinv[orow];
                    unsigned char* o = &h1g[(long long)orow * 64 + m];
#pragma unroll
                    for (int nt = 0; nt < 4; nt++) o[nt * 16] = f32_to_fp8(acc[nt][r] * dv);
                }
            }
        }
    }
}

// ---------------------------------------------------------------- gather layer 1 + fused GEMM2
// R9: fp8 h1g rows (64B): half-wave per edge, each lane loads a ushort (its 2
// channels), unpacks with v_cvt_pk_f32_fp8.  Fused GEMV (R8) now uses packed
// half2 + v_dot2_f32_f16: 32 iters x (2 LDS reads + 1 dot2) — halves the R8
// GEMV overhead.  h2g stays fp16 (disjoint buffer, R8 fix).
__global__ __launch_bounds__(256, 8)
void gather1_kernel(const unsigned short* __restrict__ h1g, const float* __restrict__ dinv,
                    const int* __restrict__ rowptr, const int* __restrict__ csr_src,
                    const void* __restrict__ bptr, const void* __restrict__ W2,
                    const int* __restrict__ flags,
                    unsigned int* __restrict__ h1b, __half* __restrict__ h2g, int N) {
    __shared__ unsigned int w2p[1024];      // 4KB: W2 packed half2 (k-pairs)
    __shared__ unsigned int h1s[4][2][32];  // 1KB: per-wave per-half h1 row (packed half2)
    bool fw = flags[1] != 0;
    // stage W2 (packed k-pairs) before any divergence/returns
    for (int j = threadIdx.x; j < 1024; j += 256) {
        int k2 = j >> 5, c0 = j & 31;
        float a = ldf(W2, (long long)(2 * k2) * 32 + c0, fw);
        float b = ldf(W2, (long long)(2 * k2 + 1) * 32 + c0, fw);
        w2p[j] = pack_h2(a, b);
    }
    __syncthreads();
    int lane = threadIdx.x & 63;
    int c = lane & 31, hf = lane >> 5;
    int wv = __builtin_amdgcn_readfirstlane(threadIdx.x >> 6);
    int n0 = (blockIdx.x * 4 + wv) * 2;
    if (n0 >= N) return;
    bool has1 = (n0 + 1 < N);
    int beg = rowptr[n0];
    int mid = rowptr[n0 + 1];
    int end = has1 ? rowptr[n0 + 2] : mid;
    const unsigned short* hL = h1g + c;     // row = 32 ushorts (64B fp8)
    float aA0 = 0.f, aA1 = 0.f;   // sum over [beg,end)
    float aN0 = 0.f, aN1 = 0.f;   // sum over [beg,mid)  (node n0)
    int p = beg;
    // 32-edge unmasked batches (16 row-loads in flight)
    for (; p + 32 <= end; p += 32) {
        unsigned short v[16]; float r[16];
#pragma unroll
        for (int u = 0; u < 16; u++) {
            int s0 = csr_src[p + 2 * u];       // uniform, consecutive -> merged s_load
            int s1 = csr_src[p + 2 * u + 1];
            int s = hf ? s1 : s0;
            r[u] = ((p + 2 * u + hf) < mid) ? 1.f : 0.f;
            v[u] = hL[(long long)s * 32];
        }
#pragma unroll
        for (int u = 0; u < 16; u++) {
            f32x2 f = fp8x2_to_f32x2(v[u]);
            aA0 += f.x; aA1 += f.y;
            aN0 = fmaf(f.x, r[u], aN0);
            aN1 = fmaf(f.y, r[u], aN1);
        }
    }
    // 16-edge unmasked batch
    for (; p + 16 <= end; p += 16) {
        unsigned short v[8]; float r[8];
#pragma unroll
        for (int u = 0; u < 8; u++) {
            int s0 = csr_src[p + 2 * u];
            int s1 = csr_src[p + 2 * u + 1];
            int s = hf ? s1 : s0;
            r[u] = ((p + 2 * u + hf) < mid) ? 1.f : 0.f;
            v[u] = hL[(long long)s * 32];
        }
#pragma unroll
        for (int u = 0; u < 8; u++) {
            f32x2 f = fp8x2_to_f32x2(v[u]);
            aA0 += f.x; aA1 += f.y;
            aN0 = fmaf(f.x, r[u], aN0);
            aN1 = fmaf(f.y, r[u], aN1);
        }
    }
    // masked tail (<16 edges)
    if (p < end) {
        unsigned short v[8]; float mk[8], r[8];
#pragma unroll
        for (int u = 0; u < 8; u++) {
            int i0 = p + 2 * u, i1 = i0 + 1;
            int s0 = csr_src[(i0 < end) ? i0 : beg];
            int s1 = csr_src[(i1 < end) ? i1 : beg];
            int s = hf ? s1 : s0;
            int i = p + 2 * u + hf;
            mk[u] = (i < end) ? 1.f : 0.f;
            r[u]  = (i < mid) ? 1.f : 0.f;
            v[u] = hL[(long long)s * 32];
        }
#pragma unroll
        for (int u = 0; u < 8; u++) {
            f32x2 f = fp8x2_to_f32x2(v[u]);
            aA0 = fmaf(f.x, mk[u], aA0);
            aA1 = fmaf(f.y, mk[u], aA1);
            aN0 = fmaf(f.x, r[u], aN0);
            aN1 = fmaf(f.y, r[u], aN1);
        }
    }
    aA0 += __shfl_xor(aA0, 32); aA1 += __shfl_xor(aA1, 32);
    aN0 += __shfl_xor(aN0, 32); aN1 += __shfl_xor(aN1, 32);
    // epilogue: half hf owns node n0+hf
    int node = n0 + hf;
    int nodeC = (node < N) ? node : n0;
    float a0 = hf ? (aA0 - aN0) : aN0;
    float a1 = hf ? (aA1 - aN1) : aN1;
    f32x2 gs = fp8x2_to_f32x2(h1g[(long long)nodeC * 32 + c]);
    float dvd = dinv[nodeC];
    float o0 = fmaxf(dvd * (a0 + gs.x) + ldf(bptr, 2 * c, fw), 0.f);
    float o1 = fmaxf(dvd * (a1 + gs.y) + ldf(bptr, 2 * c + 1, fw), 0.f);
    if (node < N)
        h1b[(long long)node * 32 + c] = pack_bf16x2(o0, o1);
    // fused GEMM2: stage packed h1 row, dot2-GEMV vs packed W2, write h2g (f16)
    h1s[wv][hf][c] = pack_h2(o0, o1);
    __threadfence_block();             // LDS write->read visibility (same wave)
    const unsigned int* hrow = h1s[wv][hf];
    float acc = 0.f;
#pragma unroll 8
    for (int k2 = 0; k2 < 32; k2++)
        acc = __builtin_amdgcn_fdot2(as_h2(hrow[k2]), as_h2(w2p[k2 * 32 + c]), acc, false);
    if (node < N)
        h2g[(long long)node * 32 + c] = __float2half(dvd * acc);
}

// ---------------------------------------------------------------- gather layer 2: node-pair combined stream (64B f16x2 rows)
__global__ __launch_bounds__(256, 8)
void gather2_kernel(const unsigned int* __restrict__ h2g, const float* __restrict__ dinv,
                    const int* __restrict__ rowptr, const int* __restrict__ csr_src,
                    const void* __restrict__ bptr, const int* __restrict__ flags,
                    unsigned int* __restrict__ h2b, int N) {
    bool fw = flags[1] != 0;
    int lane = threadIdx.x & 63;
    int c = lane & 15, sub = lane >> 4;
    int wv = __builtin_amdgcn_readfirstlane(threadIdx.x >> 6);
    int n0 = (blockIdx.x * 4 + wv) * 2;
    if (n0 >= N) return;
    bool has1 = (n0 + 1 < N);
    int beg = rowptr[n0];
    int mid = rowptr[n0 + 1];
    int end = has1 ? rowptr[n0 + 2] : mid;
    const unsigned int* hL = h2g + c;
    float aA0 = 0.f, aA1 = 0.f, aN0 = 0.f, aN1 = 0.f;
    int p = beg;
    // 32-edge unmasked batches (8 loads in flight)
    for (; p + 32 <= end; p += 32) {
        unsigned int v[8]; float r[8];
#pragma unroll
        for (int u = 0; u < 8; u++) {
            int i0 = p + 4 * u;
            int sa0 = csr_src[i0], sa1 = csr_src[i0 + 1];
            int sa2 = csr_src[i0 + 2], sa3 = csr_src[i0 + 3];
            int sA = (sub & 1) ? sa1 : sa0;
            int sB = (sub & 1) ? sa3 : sa2;
            int s  = (sub & 2) ? sB : sA;
            r[u] = ((i0 + sub) < mid) ? 1.f : 0.f;
            v[u] = hL[(long long)s * 16];
        }
#pragma unroll
        for (int u = 0; u < 8; u++) {
            float2 f = __half22float2(*(const __half2*)&v[u]);
            aA0 += f.x; aA1 += f.y;
            aN0 = fmaf(f.x, r[u], aN0);
            aN1 = fmaf(f.y, r[u], aN1);
        }
    }
    // 16-edge unmasked batch
    for (; p + 16 <= end; p += 16) {
        unsigned int v[4]; float r[4];
#pragma unroll
        for (int u = 0; u < 4; u++) {
            int i0 = p + 4 * u;
            int sa0 = csr_src[i0], sa1 = csr_src[i0 + 1];
            int sa2 = csr_src[i0 + 2], sa3 = csr_src[i0 + 3];
            int sA = (sub & 1) ? sa1 : sa0;
            int sB = (sub & 1) ? sa3 : sa2;
            int s  = (sub & 2) ? sB : sA;
            r[u] = ((i0 + sub) < mid) ? 1.f : 0.f;
            v[u] = hL[(long long)s * 16];
        }
#pragma unroll
        for (int u = 0; u < 4; u++) {
            float2 f = __half22float2(*(const __half2*)&v[u]);
            aA0 += f.x; aA1 += f.y;
            aN0 = fmaf(f.x, r[u], aN0);
            aN1 = fmaf(f.y, r[u], aN1);
        }
    }
    // masked tail (<16 edges)
    if (p < end) {
        unsigned int v[4]; float mk[4], r[4];
#pragma unroll
        for (int u = 0; u < 4; u++) {
            int i0 = p + 4 * u;
            int sa0 = csr_src[(i0     < end) ? i0     : beg];
            int sa1 = csr_src[(i0 + 1 < end) ? i0 + 1 : beg];
            int sa2 = csr_src[(i0 + 2 < end) ? i0 + 2 : beg];
            int sa3 = csr_src[(i0 + 3 < end) ? i0 + 3 : beg];
            int sA = (sub & 1) ? sa1 : sa0;
            int sB = (sub & 1) ? sa3 : sa2;
            int s  = (sub & 2) ? sB : sA;
            int i = i0 + sub;
            mk[u] = (i < end) ? 1.f : 0.f;
            r[u]  = (i < mid) ? 1.f : 0.f;
            v[u] = hL[(long long)s * 16];
        }
#pragma unroll
        for (int u = 0; u < 4; u++) {
            float2 f = __half22float2(*(const __half2*)&v[u]);
            aA0 = fmaf(f.x, mk[u], aA0);
            aA1 = fmaf(f.y, mk[u], aA1);
            aN0 = fmaf(f.x, r[u], aN0);
            aN1 = fmaf(f.y, r[u], aN1);
        }
    }
    aA0 += __shfl_xor(aA0, 16); aA1 += __shfl_xor(aA1, 16);
    aN0 += __shfl_xor(aN0, 16); aN1 += __shfl_xor(aN1, 16);
    aA0 += __shfl_xor(aA0, 32); aA1 += __shfl_xor(aA1, 32);
    aN0 += __shfl_xor(aN0, 32); aN1 += __shfl_xor(aN1, 32);
    // sub 0 stores n0 (aN), sub 1 stores n1 (aA - aN): contiguous 128B store
    if (sub < 2) {
        int node = n0 + sub;
        if (node < N) {
            float a0 = sub ? (aA0 - aN0) : aN0;
            float a1 = sub ? (aA1 - aN1) : aN1;
            unsigned int gsv = h2g[(long long)node * 16 + c];
            float2 gs = __half22float2(*(const __half2*)&gsv);
            float dvd = dinv[node];
            float o0 = dvd * (a0 + gs.x) + ldf(bptr, 2 * c, fw);
            float o1 = dvd * (a1 + gs.y) + ldf(bptr, 2 * c + 1, fw);
            h2b[(long long)node * 16 + c] = pack_bf16x2(o0, o1);
        }
    }
}

// ---------------------------------------------------------------- final (MFMA): [x|h1b|h2b]@Wl + bl -> log_softmax
__global__ __launch_bounds__(256, 2)
void final_mfma_kernel(const void* __restrict__ x, const short* __restrict__ xb,
                       const short* __restrict__ h1b,
                       const short* __restrict__ h2b, const bf16* __restrict__ Bpack,
                       const void* __restrict__ bl, const int* __restrict__ flags,
                       void* __restrict__ out, int N) {
    bool fw = flags[1] != 0, fx = flags[0] != 0;
    const short* xs = fx ? xb : (const short*)x;
    int lane = threadIdx.x & 63, wave = threadIdx.x >> 6;
    int m = lane & 15, quad = lane >> 4;
    int r0 = blockIdx.x * 64 + wave * 16;
    if (r0 >= N) return;
    const short8* bp = (const short8*)Bpack;
    short8 B[14];
#pragma unroll
    for (int i = 0; i < 14; i++) B[i] = bp[i * 64 + lane];
    f32x4 acc0 = {0.f,0.f,0.f,0.f}, acc1 = {0.f,0.f,0.f,0.f};
    bool full = (r0 + 16 <= N);
    int row = r0 + m;
    bool rowok = full || (row < N);
#pragma unroll
    for (int s = 0; s < 7; s++) {
        short8 A = {0,0,0,0,0,0,0,0};
        if (rowok) {
            const short* p;
            if (s < 4)      p = &xs [(long long)row * 128 + s * 32 + quad * 8];
            else if (s < 6) p = &h1b[(long long)row * 64 + (s - 4) * 32 + quad * 8];
            else            p = &h2b[(long long)row * 32 + quad * 8];
            A = *(const short8*)p;
        }
        acc0 = MFMA16(A, B[s * 2 + 0], acc0);
        acc1 = MFMA16(A, B[s * 2 + 1], acc1);
    }
    float bl0 = ldf(bl, m, fw), bl1 = ldf(bl, m + 16, fw);
#pragma unroll
    for (int r = 0; r < 4; r++) {
        float v0 = acc0[r] + bl0, v1 = acc1[r] + bl1;
        float mx = fmaxf(v0, v1);
#pragma unroll
        for (int o = 8; o > 0; o >>= 1) mx = fmaxf(mx, __shfl_xor(mx, o));
        float sm = __expf(v0 - mx) + __expf(v1 - mx);
#pragma unroll
        for (int o = 8; o > 0; o >>= 1) sm += __shfl_xor(sm, o);
        float lse = mx + __logf(sm);
        int orow = r0 + quad * 4 + r;
        if (orow < N) {
            if (fx) {
                ((float*)out)[(long long)orow * 32 + m]      = v0 - lse;
                ((float*)out)[(long long)orow * 32 + 16 + m] = v1 - lse;
            } else {
                ((bf16*)out)[(long long)orow * 32 + m]      = __float2bfloat16(v0 - lse);
                ((bf16*)out)[(long long)orow * 32 + 16 + m] = __float2bfloat16(v1 - lse);
            }
        }
    }
}

extern "C" void kernel_launch(void* const* d_in, const int* in_sizes, int n_in,
                              void* d_out, int out_size, void* d_ws, size_t ws_size,
                              hipStream_t stream) {
    const void* x  = d_in[0];
    const int*  ei = (const int*)d_in[1];
    const void* W1 = d_in[2];
    const void* b1 = d_in[3];
    const void* W2 = d_in[4];
    const void* b2 = d_in[5];
    const void* Wl = d_in[6];
    const void* bl = d_in[7];

    int N = in_sizes[0] / 128;
    int E = in_sizes[1] / 2;

    int shift = 9;
    while (((N + (1 << shift) - 1) >> shift) > 256 && shift < 10) shift++;
    int NB = (N + (1 << shift) - 1) >> shift;   // 196 at N=100k

    // ws layout (4B units):
    // [flags 16 | bucketCount 256 | bucketBase 272 (dead) | bcursor 256 | dinv N | rowptr N+16 |
    //  Bp1 4096 | Bp2 1024 (dead) | Bp3 3584 | csr_src E | xb N*64 |
    //  A N*64: h1g fp8 [0,N*16) | h2g f16 [N*16,N*32) | h2b [N*48,N*64)   (ebuf int2 E*2<=N*64, dead before gemm1)
    //  | h1b N*32]
    int* ip      = (int*)d_ws;
    int* flags   = ip;
    int* bucketCount = ip + 16;
    int* bucketBase  = bucketCount + 256;   // dead, layout kept
    int* bcursor     = bucketBase + 272;
    float* dinv  = (float*)(bcursor + 256);
    int* rowptr  = (int*)(dinv + N);
    bf16* Bp1    = (bf16*)(rowptr + N + 16);
    bf16* Bp2    = (bf16*)((int*)Bp1 + 4096);  // dead
    bf16* Bp3    = (bf16*)((int*)Bp2 + 1024);
    int* csr_src = (int*)Bp3 + 3584;
    short* xb    = (short*)(csr_src + E);                 // N*64 ints
    int*   Ai    = (int*)xb + (size_t)N * 64;             // region A: N*64 ints
    int2*  ebuf  = (int2*)Ai;                             // E*2 ints (dead before gemm1)
    unsigned char* h1g = (unsigned char*)Ai;              // fp8, [0, N*16) ints = N*64 bytes
    __half* h2g  = (__half*)(Ai + (size_t)N * 16);        // [N*16, N*32) ints — disjoint (R8 fix)
    unsigned int* h2b = (unsigned int*)(Ai + (size_t)N * 48);  // [N*48, N*64) ints
    unsigned int* h1b = (unsigned int*)(Ai + (size_t)N * 64);  // N*32 uints

    // zero flags + bucketCount + bucketBase + bcursor (contiguous 800 ints)
    hipMemsetAsync(ip, 0, 800 * sizeof(int), stream);

    int nchunk = (E + 4095) / 4096;
    bhist_kernel<<<nchunk + 2, 256, 0, stream>>>(ei, E, x, W1, Wl, shift, NB, nchunk,
                                                 flags, bucketCount, Bp1, Bp3);
    bpart_kernel<<<nchunk, 256, 0, stream>>>(ei, E, shift, NB, bucketCount, bcursor, ebuf);
    bbuild_kernel<<<NB, 256, 0, stream>>>(ebuf, bucketCount, shift, N, E, rowptr, dinv, csr_src);

    gemm1_mfma_kernel<<<(N + 127) / 128, 256, 0, stream>>>(x, Bp1, dinv, flags, h1g, xb, N);
    gather1_kernel<<<(N + 7) / 8, 256, 0, stream>>>((const unsigned short*)h1g, dinv, rowptr, csr_src,
                                                    b1, W2, flags, h1b, h2g, N);
    gather2_kernel<<<(N + 7) / 8, 256, 0, stream>>>((const unsigned int*)h2g, dinv, rowptr, csr_src,
                                                    b2, flags, h2b, N);
    final_mfma_kernel<<<(N + 63) / 64, 256, 0, stream>>>(x, (const short*)xb, (const short*)h1b,
                                                         (const short*)h2b, Bp3, bl, flags, d_out, N);
}